// Round 1
// baseline (631.836 us; speedup 1.0000x reference)
//
#include <hip/hip_runtime.h>

// ---------------------------------------------------------------------------
// GAT policy module: 2x GAT layer (head-mean) + mean-pool + 2 MLP heads.
// Round 0: correctness-first fp32 implementation.
// ---------------------------------------------------------------------------

#define G_GRAPHS 64

__device__ inline void atomicMaxF(float* addr, float val) {
    // IEEE-754 ordered-int trick. Init pattern 0xFFFFFFFF (negative NaN)
    // behaves as -inf: signed int -1 loses to any non-negative float bits,
    // unsigned max loses to any negative float bits.
    if (val >= 0.0f) atomicMax((int*)addr, __float_as_int(val));
    else             atomicMin((unsigned int*)addr, (unsigned int)__float_as_int(val));
}

// ---------------------------------------------------------------------------
// fp32 register-tiled GEMM: C[M,N] = A[M,K] @ B[K,N]
// BM=64, BN=64, BK=16, 256 threads, 4x4 accum per thread.
// Requires: K % 16 == 0, N % 64 == 0 (true here: K=128/64, N=256/64).
// ---------------------------------------------------------------------------
__global__ __launch_bounds__(256) void gemm_fp32(
        const float* __restrict__ A, const float* __restrict__ B,
        float* __restrict__ C, int M, int N, int K)
{
    constexpr int BM = 64, BN = 64, BK = 16;
    __shared__ float As[BK][BM];   // transposed A tile
    __shared__ float Bs[BK][BN];
    const int tid = threadIdx.x;
    const int tx = tid % 16;       // col group (4 cols each)
    const int ty = tid / 16;       // row group (4 rows each)
    const int row0 = blockIdx.x * BM;
    const int col0 = blockIdx.y * BN;

    float acc[4][4] = {};

    for (int kt = 0; kt < K; kt += BK) {
        // A tile: 64 rows x 16 cols, one float4 per thread
        {
            int r  = tid >> 2;           // 0..63
            int c4 = (tid & 3) * 4;      // 0,4,8,12
            int gr = row0 + r;
            float4 v = make_float4(0.f, 0.f, 0.f, 0.f);
            if (gr < M) v = *reinterpret_cast<const float4*>(&A[(size_t)gr * K + kt + c4]);
            As[c4 + 0][r] = v.x; As[c4 + 1][r] = v.y;
            As[c4 + 2][r] = v.z; As[c4 + 3][r] = v.w;
        }
        // B tile: 16 rows x 64 cols, one float4 per thread
        {
            int r  = tid >> 4;           // 0..15
            int c4 = (tid & 15) * 4;     // 0..60
            float4 v = *reinterpret_cast<const float4*>(&B[(size_t)(kt + r) * N + col0 + c4]);
            *reinterpret_cast<float4*>(&Bs[r][c4]) = v;
        }
        __syncthreads();
        #pragma unroll
        for (int k = 0; k < BK; k++) {
            float ra[4], rb[4];
            #pragma unroll
            for (int i = 0; i < 4; i++) ra[i] = As[k][ty * 4 + i];
            #pragma unroll
            for (int j = 0; j < 4; j++) rb[j] = Bs[k][tx * 4 + j];
            #pragma unroll
            for (int i = 0; i < 4; i++)
                #pragma unroll
                for (int j = 0; j < 4; j++)
                    acc[i][j] += ra[i] * rb[j];
        }
        __syncthreads();
    }

    #pragma unroll
    for (int i = 0; i < 4; i++) {
        int gr = row0 + ty * 4 + i;
        if (gr < M) {
            #pragma unroll
            for (int j = 0; j < 4; j++)
                C[(size_t)gr * N + col0 + tx * 4 + j] = acc[i][j];
        }
    }
}

// ---------------------------------------------------------------------------
// a_src[n,h] = sum_c h[n,h,c]*att_s[h,c] ; a_dst likewise. Thread per (n,h).
// ---------------------------------------------------------------------------
template<int H, int C>
__global__ __launch_bounds__(256) void att_coef(
        const float* __restrict__ hfeat, const float* __restrict__ att_s,
        const float* __restrict__ att_d, float* __restrict__ a_s,
        float* __restrict__ a_d, int N)
{
    int idx = blockIdx.x * 256 + threadIdx.x;
    if (idx >= N * H) return;
    int n = idx / H, h = idx % H;
    const float* hp = hfeat + (size_t)n * (H * C) + h * C;
    const float* as = att_s + h * C;
    const float* ad = att_d + h * C;
    float ss = 0.f, sd = 0.f;
    #pragma unroll 8
    for (int c = 0; c < C; c++) {
        float v = hp[c];
        ss += v * as[c];
        sd += v * ad[c];
    }
    a_s[idx] = ss;
    a_d[idx] = sd;
}

// ---------------------------------------------------------------------------
// Edge pass 1: e = leaky_relu(a_src[src]+a_dst[dst]); segment-max into mmax.
// ---------------------------------------------------------------------------
template<int H>
__global__ __launch_bounds__(256) void edge_scores(
        const int* __restrict__ ei, const float* __restrict__ a_s,
        const float* __restrict__ a_d, float* __restrict__ e,
        float* __restrict__ mmax, int E0, int Etot)
{
    int idx = blockIdx.x * 256 + threadIdx.x;
    if (idx >= Etot) return;
    int src = (idx < E0) ? ei[idx]      : (idx - E0);
    int dst = (idx < E0) ? ei[E0 + idx] : (idx - E0);
    #pragma unroll
    for (int h = 0; h < H; h++) {
        float v = a_s[src * H + h] + a_d[dst * H + h];
        v = (v > 0.f) ? v : 0.2f * v;          // leaky_relu, slope 0.2
        e[(size_t)idx * H + h] = v;
        atomicMaxF(&mmax[dst * H + h], v);
    }
}

// ---------------------------------------------------------------------------
// Edge pass 2: ee = exp(e - m[dst]); segment-sum into denom. In-place on e.
// ---------------------------------------------------------------------------
template<int H>
__global__ __launch_bounds__(256) void edge_exp(
        const int* __restrict__ ei, float* __restrict__ e,
        const float* __restrict__ mmax, float* __restrict__ denom,
        int E0, int Etot)
{
    int idx = blockIdx.x * 256 + threadIdx.x;
    if (idx >= Etot) return;
    int dst = (idx < E0) ? ei[E0 + idx] : (idx - E0);
    #pragma unroll
    for (int h = 0; h < H; h++) {
        float ev = __expf(e[(size_t)idx * H + h] - mmax[dst * H + h]);
        e[(size_t)idx * H + h] = ev;
        atomicAdd(&denom[dst * H + h], ev);
    }
}

// ---------------------------------------------------------------------------
// Edge pass 3: agg[dst,c] += sum_h (ee[h]/denom[dst,h]) * h[src,h,c]
// (head-reduced per edge -> C atomics/edge instead of H*C). C lanes per edge.
// ---------------------------------------------------------------------------
template<int H, int C>
__global__ __launch_bounds__(256) void edge_aggregate(
        const int* __restrict__ ei, const float* __restrict__ hfeat,
        const float* __restrict__ ee, const float* __restrict__ denom,
        float* __restrict__ agg, int E0, int Etot)
{
    constexpr int EPB = 256 / C;
    int e = blockIdx.x * EPB + threadIdx.x / C;
    int c = threadIdx.x % C;
    if (e >= Etot) return;
    int src = (e < E0) ? ei[e]      : (e - E0);
    int dst = (e < E0) ? ei[E0 + e] : (e - E0);
    float acc = 0.f;
    #pragma unroll
    for (int h = 0; h < H; h++) {
        float alpha = ee[(size_t)e * H + h] / (denom[dst * H + h] + 1e-16f);
        acc += alpha * hfeat[(size_t)src * (H * C) + h * C + c];
    }
    atomicAdd(&agg[(size_t)dst * C + c], acc);
}

// ---------------------------------------------------------------------------
// Node epilogue: out = relu(agg * (1/H) + bias)   (in-place safe)
// ---------------------------------------------------------------------------
template<int C>
__global__ __launch_bounds__(256) void node_finish(
        const float* __restrict__ agg, const float* __restrict__ bias,
        float* __restrict__ out, float invH, int N)
{
    int idx = blockIdx.x * 256 + threadIdx.x;
    if (idx >= N * C) return;
    int c = idx % C;
    float v = agg[idx] * invH + bias[c];
    out[idx] = fmaxf(v, 0.f);
}

// ---------------------------------------------------------------------------
// Global mean-pool partials: atomics into pool[G,32], cnt[G].
// ---------------------------------------------------------------------------
__global__ __launch_bounds__(256) void pool_kernel(
        const float* __restrict__ h2, const int* __restrict__ batch,
        float* __restrict__ pool, float* __restrict__ cnt, int N)
{
    int idx = blockIdx.x * 256 + threadIdx.x;
    if (idx >= N * 32) return;
    int n = idx / 32, c = idx % 32;
    int g = batch[n];
    atomicAdd(&pool[g * 32 + c], h2[idx]);
    if (c == 0) atomicAdd(&cnt[g], 1.0f);
}

// ---------------------------------------------------------------------------
// Heads: emb = pool/cnt ; two 32->16->1 MLPs + sigmoid. One thread per graph.
// Output layout: out[0:64] = halt, out[64:128] = cont  (reference returns
// (halt, cont)).
// ---------------------------------------------------------------------------
__global__ __launch_bounds__(64) void heads_kernel(
        const float* __restrict__ pool, const float* __restrict__ cnt,
        const float* __restrict__ cW1, const float* __restrict__ cb1,
        const float* __restrict__ cW2, const float* __restrict__ cb2,
        const float* __restrict__ hW1, const float* __restrict__ hb1,
        const float* __restrict__ hW2, const float* __restrict__ hb2,
        float* __restrict__ out)
{
    int g = threadIdx.x;
    if (g >= G_GRAPHS) return;
    float inv = 1.0f / fmaxf(cnt[g], 1.0f);
    float emb[32];
    #pragma unroll
    for (int c = 0; c < 32; c++) emb[c] = pool[g * 32 + c] * inv;

    // continue head
    float sc = cb2[0];
    #pragma unroll
    for (int j = 0; j < 16; j++) {
        float s = cb1[j];
        #pragma unroll
        for (int c = 0; c < 32; c++) s += emb[c] * cW1[c * 16 + j];
        sc += fmaxf(s, 0.f) * cW2[j];
    }
    float cont = 1.0f / (1.0f + __expf(-sc));

    // halt head
    float sh = hb2[0];
    #pragma unroll
    for (int j = 0; j < 16; j++) {
        float s = hb1[j];
        #pragma unroll
        for (int c = 0; c < 32; c++) s += emb[c] * hW1[c * 16 + j];
        sh += fmaxf(s, 0.f) * hW2[j];
    }
    float halt = 1.0f / (1.0f + __expf(-sh));

    out[g] = halt;
    out[G_GRAPHS + g] = cont;
}

// ---------------------------------------------------------------------------
extern "C" void kernel_launch(void* const* d_in, const int* in_sizes, int n_in,
                              void* d_out, int out_size, void* d_ws, size_t ws_size,
                              hipStream_t stream)
{
    const float* x   = (const float*)d_in[0];
    const int*   ei  = (const int*)  d_in[1];
    const int*   bat = (const int*)  d_in[2];
    const float* W1  = (const float*)d_in[3];
    const float* as1 = (const float*)d_in[4];
    const float* ad1 = (const float*)d_in[5];
    const float* b1  = (const float*)d_in[6];
    const float* W2  = (const float*)d_in[7];
    const float* as2 = (const float*)d_in[8];
    const float* ad2 = (const float*)d_in[9];
    const float* b2  = (const float*)d_in[10];
    const float* cW1 = (const float*)d_in[11];
    const float* cb1 = (const float*)d_in[12];
    const float* cW2 = (const float*)d_in[13];
    const float* cb2 = (const float*)d_in[14];
    const float* hW1 = (const float*)d_in[15];
    const float* hb1 = (const float*)d_in[16];
    const float* hW2 = (const float*)d_in[17];
    const float* hb2 = (const float*)d_in[18];

    const int N    = in_sizes[2];           // 20000
    const int E0   = in_sizes[1] / 2;       // 320000
    const int Etot = E0 + N;                // + self loops
    const int IN   = in_sizes[0] / N;       // 128

    // ---- workspace carve (floats) ----
    float* w = (float*)d_ws;
    size_t o = 0;
    float* h1pre = w + o; o += (size_t)N * 256;   // x@W1  [N,4,64]
    float* a_s1  = w + o; o += (size_t)N * 4;
    float* a_d1  = w + o; o += (size_t)N * 4;
    float* m1    = w + o; o += (size_t)N * 4;
    float* den1  = w + o; o += (size_t)N * 4;
    float* e1    = w + o; o += (size_t)Etot * 4;
    float* agg1  = w + o; o += (size_t)N * 64;    // becomes h1 (in-place relu)
    float* h2pre = w + o; o += (size_t)N * 64;    // h1@W2  [N,2,32]
    float* a_s2  = w + o; o += (size_t)N * 2;
    float* a_d2  = w + o; o += (size_t)N * 2;
    float* m2    = w + o; o += (size_t)N * 2;
    float* den2  = w + o; o += (size_t)N * 2;
    float* e2    = w + o; o += (size_t)Etot * 2;
    float* agg2  = w + o; o += (size_t)N * 32;    // becomes h2 (in-place relu)
    float* pool  = w + o; o += (size_t)G_GRAPHS * 32;
    float* cnt   = w + o; o += (size_t)G_GRAPHS;
    (void)ws_size; (void)n_in; (void)out_size;

    // ---- init scratch (ws is poisoned 0xAA before every call) ----
    hipMemsetAsync(m1,   0xFF, (size_t)N * 4  * sizeof(float), stream); // -inf-like
    hipMemsetAsync(den1, 0,    (size_t)N * 4  * sizeof(float), stream);
    hipMemsetAsync(agg1, 0,    (size_t)N * 64 * sizeof(float), stream);
    hipMemsetAsync(m2,   0xFF, (size_t)N * 2  * sizeof(float), stream);
    hipMemsetAsync(den2, 0,    (size_t)N * 2  * sizeof(float), stream);
    hipMemsetAsync(agg2, 0,    (size_t)N * 32 * sizeof(float), stream);
    hipMemsetAsync(pool, 0,    (size_t)(G_GRAPHS * 32 + G_GRAPHS) * sizeof(float), stream);

    const dim3 blk(256);
    const int eb = (Etot + 255) / 256;

    // ---- layer 1: GAT(128 -> 4 heads x 64, head-mean) + relu ----
    gemm_fp32<<<dim3((N + 63) / 64, 256 / 64), blk, 0, stream>>>(x, W1, h1pre, N, 256, IN);
    att_coef<4, 64><<<(N * 4 + 255) / 256, blk, 0, stream>>>(h1pre, as1, ad1, a_s1, a_d1, N);
    edge_scores<4><<<eb, blk, 0, stream>>>(ei, a_s1, a_d1, e1, m1, E0, Etot);
    edge_exp<4><<<eb, blk, 0, stream>>>(ei, e1, m1, den1, E0, Etot);
    edge_aggregate<4, 64><<<(Etot + 3) / 4, blk, 0, stream>>>(ei, h1pre, e1, den1, agg1, E0, Etot);
    node_finish<64><<<(N * 64 + 255) / 256, blk, 0, stream>>>(agg1, b1, agg1, 0.25f, N);

    // ---- layer 2: GAT(64 -> 2 heads x 32, head-mean) + relu ----
    gemm_fp32<<<dim3((N + 63) / 64, 1), blk, 0, stream>>>(agg1, W2, h2pre, N, 64, 64);
    att_coef<2, 32><<<(N * 2 + 255) / 256, blk, 0, stream>>>(h2pre, as2, ad2, a_s2, a_d2, N);
    edge_scores<2><<<eb, blk, 0, stream>>>(ei, a_s2, a_d2, e2, m2, E0, Etot);
    edge_exp<2><<<eb, blk, 0, stream>>>(ei, e2, m2, den2, E0, Etot);
    edge_aggregate<2, 32><<<(Etot + 7) / 8, blk, 0, stream>>>(ei, h2pre, e2, den2, agg2, E0, Etot);
    node_finish<32><<<(N * 32 + 255) / 256, blk, 0, stream>>>(agg2, b2, agg2, 0.5f, N);

    // ---- pool + heads ----
    pool_kernel<<<(N * 32 + 255) / 256, blk, 0, stream>>>(agg2, bat, pool, cnt, N);
    heads_kernel<<<1, 64, 0, stream>>>(pool, cnt, cW1, cb1, cW2, cb2,
                                       hW1, hb1, hW2, hb2, (float*)d_out);
}

// Round 2
// 495.415 us; speedup vs baseline: 1.2754x; 1.2754x over previous
//
#include <hip/hip_runtime.h>

// ---------------------------------------------------------------------------
// GAT policy module: 2x GAT layer (head-mean) + mean-pool + 2 MLP heads.
// Round 1: replace atomic global-mean-pool (140us, 312-way atomic contention
// on 2048 addrs) with one-block-per-graph segmented reduction (batch sorted).
// ---------------------------------------------------------------------------

#define G_GRAPHS 64

__device__ inline void atomicMaxF(float* addr, float val) {
    // IEEE-754 ordered-int trick. Init pattern 0xFFFFFFFF (negative NaN)
    // behaves as -inf: signed int -1 loses to any non-negative float bits,
    // unsigned max loses to any negative float bits.
    if (val >= 0.0f) atomicMax((int*)addr, __float_as_int(val));
    else             atomicMin((unsigned int*)addr, (unsigned int)__float_as_int(val));
}

// ---------------------------------------------------------------------------
// fp32 register-tiled GEMM: C[M,N] = A[M,K] @ B[K,N]
// BM=64, BN=64, BK=16, 256 threads, 4x4 accum per thread.
// Requires: K % 16 == 0, N % 64 == 0 (true here: K=128/64, N=256/64).
// ---------------------------------------------------------------------------
__global__ __launch_bounds__(256) void gemm_fp32(
        const float* __restrict__ A, const float* __restrict__ B,
        float* __restrict__ C, int M, int N, int K)
{
    constexpr int BM = 64, BN = 64, BK = 16;
    __shared__ float As[BK][BM];   // transposed A tile
    __shared__ float Bs[BK][BN];
    const int tid = threadIdx.x;
    const int tx = tid % 16;       // col group (4 cols each)
    const int ty = tid / 16;       // row group (4 rows each)
    const int row0 = blockIdx.x * BM;
    const int col0 = blockIdx.y * BN;

    float acc[4][4] = {};

    for (int kt = 0; kt < K; kt += BK) {
        // A tile: 64 rows x 16 cols, one float4 per thread
        {
            int r  = tid >> 2;           // 0..63
            int c4 = (tid & 3) * 4;      // 0,4,8,12
            int gr = row0 + r;
            float4 v = make_float4(0.f, 0.f, 0.f, 0.f);
            if (gr < M) v = *reinterpret_cast<const float4*>(&A[(size_t)gr * K + kt + c4]);
            As[c4 + 0][r] = v.x; As[c4 + 1][r] = v.y;
            As[c4 + 2][r] = v.z; As[c4 + 3][r] = v.w;
        }
        // B tile: 16 rows x 64 cols, one float4 per thread
        {
            int r  = tid >> 4;           // 0..15
            int c4 = (tid & 15) * 4;     // 0..60
            float4 v = *reinterpret_cast<const float4*>(&B[(size_t)(kt + r) * N + col0 + c4]);
            *reinterpret_cast<float4*>(&Bs[r][c4]) = v;
        }
        __syncthreads();
        #pragma unroll
        for (int k = 0; k < BK; k++) {
            float ra[4], rb[4];
            #pragma unroll
            for (int i = 0; i < 4; i++) ra[i] = As[k][ty * 4 + i];
            #pragma unroll
            for (int j = 0; j < 4; j++) rb[j] = Bs[k][tx * 4 + j];
            #pragma unroll
            for (int i = 0; i < 4; i++)
                #pragma unroll
                for (int j = 0; j < 4; j++)
                    acc[i][j] += ra[i] * rb[j];
        }
        __syncthreads();
    }

    #pragma unroll
    for (int i = 0; i < 4; i++) {
        int gr = row0 + ty * 4 + i;
        if (gr < M) {
            #pragma unroll
            for (int j = 0; j < 4; j++)
                C[(size_t)gr * N + col0 + tx * 4 + j] = acc[i][j];
        }
    }
}

// ---------------------------------------------------------------------------
// a_src[n,h] = sum_c h[n,h,c]*att_s[h,c] ; a_dst likewise. Thread per (n,h).
// ---------------------------------------------------------------------------
template<int H, int C>
__global__ __launch_bounds__(256) void att_coef(
        const float* __restrict__ hfeat, const float* __restrict__ att_s,
        const float* __restrict__ att_d, float* __restrict__ a_s,
        float* __restrict__ a_d, int N)
{
    int idx = blockIdx.x * 256 + threadIdx.x;
    if (idx >= N * H) return;
    int n = idx / H, h = idx % H;
    const float* hp = hfeat + (size_t)n * (H * C) + h * C;
    const float* as = att_s + h * C;
    const float* ad = att_d + h * C;
    float ss = 0.f, sd = 0.f;
    #pragma unroll 8
    for (int c = 0; c < C; c++) {
        float v = hp[c];
        ss += v * as[c];
        sd += v * ad[c];
    }
    a_s[idx] = ss;
    a_d[idx] = sd;
}

// ---------------------------------------------------------------------------
// Edge pass 1: e = leaky_relu(a_src[src]+a_dst[dst]); segment-max into mmax.
// ---------------------------------------------------------------------------
template<int H>
__global__ __launch_bounds__(256) void edge_scores(
        const int* __restrict__ ei, const float* __restrict__ a_s,
        const float* __restrict__ a_d, float* __restrict__ e,
        float* __restrict__ mmax, int E0, int Etot)
{
    int idx = blockIdx.x * 256 + threadIdx.x;
    if (idx >= Etot) return;
    int src = (idx < E0) ? ei[idx]      : (idx - E0);
    int dst = (idx < E0) ? ei[E0 + idx] : (idx - E0);
    #pragma unroll
    for (int h = 0; h < H; h++) {
        float v = a_s[src * H + h] + a_d[dst * H + h];
        v = (v > 0.f) ? v : 0.2f * v;          // leaky_relu, slope 0.2
        e[(size_t)idx * H + h] = v;
        atomicMaxF(&mmax[dst * H + h], v);
    }
}

// ---------------------------------------------------------------------------
// Edge pass 2: ee = exp(e - m[dst]); segment-sum into denom. In-place on e.
// ---------------------------------------------------------------------------
template<int H>
__global__ __launch_bounds__(256) void edge_exp(
        const int* __restrict__ ei, float* __restrict__ e,
        const float* __restrict__ mmax, float* __restrict__ denom,
        int E0, int Etot)
{
    int idx = blockIdx.x * 256 + threadIdx.x;
    if (idx >= Etot) return;
    int dst = (idx < E0) ? ei[E0 + idx] : (idx - E0);
    #pragma unroll
    for (int h = 0; h < H; h++) {
        float ev = __expf(e[(size_t)idx * H + h] - mmax[dst * H + h]);
        e[(size_t)idx * H + h] = ev;
        atomicAdd(&denom[dst * H + h], ev);
    }
}

// ---------------------------------------------------------------------------
// Edge pass 3: agg[dst,c] += sum_h (ee[h]/denom[dst,h]) * h[src,h,c]
// (head-reduced per edge -> C atomics/edge instead of H*C). C lanes per edge.
// ---------------------------------------------------------------------------
template<int H, int C>
__global__ __launch_bounds__(256) void edge_aggregate(
        const int* __restrict__ ei, const float* __restrict__ hfeat,
        const float* __restrict__ ee, const float* __restrict__ denom,
        float* __restrict__ agg, int E0, int Etot)
{
    constexpr int EPB = 256 / C;
    int e = blockIdx.x * EPB + threadIdx.x / C;
    int c = threadIdx.x % C;
    if (e >= Etot) return;
    int src = (e < E0) ? ei[e]      : (e - E0);
    int dst = (e < E0) ? ei[E0 + e] : (e - E0);
    float acc = 0.f;
    #pragma unroll
    for (int h = 0; h < H; h++) {
        float alpha = ee[(size_t)e * H + h] / (denom[dst * H + h] + 1e-16f);
        acc += alpha * hfeat[(size_t)src * (H * C) + h * C + c];
    }
    atomicAdd(&agg[(size_t)dst * C + c], acc);
}

// ---------------------------------------------------------------------------
// Node epilogue: out = relu(agg * (1/H) + bias)   (in-place safe)
// ---------------------------------------------------------------------------
template<int C>
__global__ __launch_bounds__(256) void node_finish(
        const float* __restrict__ agg, const float* __restrict__ bias,
        float* __restrict__ out, float invH, int N)
{
    int idx = blockIdx.x * 256 + threadIdx.x;
    if (idx >= N * C) return;
    int c = idx % C;
    float v = agg[idx] * invH + bias[c];
    out[idx] = fmaxf(v, 0.f);
}

// ---------------------------------------------------------------------------
// Global mean pool, one block per graph (batch is SORTED -> contiguous
// segments; binary search the boundaries, reduce through LDS, no atomics).
// 256 threads = 8 node-rows x 32 channels. Writes emb[g,32] directly.
// ---------------------------------------------------------------------------
__global__ __launch_bounds__(256) void pool_pergraph(
        const float* __restrict__ h2, const int* __restrict__ batch,
        float* __restrict__ emb, int N)
{
    const int g = blockIdx.x;
    const int c = threadIdx.x & 31;     // channel
    const int r = threadIdx.x >> 5;     // node row 0..7

    __shared__ int bounds[2];
    if (threadIdx.x < 2) {
        // lower_bound(batch, g + threadIdx.x)
        int target = g + (int)threadIdx.x;
        int lo = 0, hi = N;
        while (lo < hi) {
            int mid = (lo + hi) >> 1;
            if (batch[mid] < target) lo = mid + 1; else hi = mid;
        }
        bounds[threadIdx.x] = lo;
    }
    __syncthreads();
    const int lo = bounds[0], hi = bounds[1];

    float acc = 0.f;
    for (int n = lo + r; n < hi; n += 8)
        acc += h2[(size_t)n * 32 + c];

    __shared__ float red[8][32];
    red[r][c] = acc;
    __syncthreads();
    if (r == 0) {
        float s = 0.f;
        #pragma unroll
        for (int i = 0; i < 8; i++) s += red[i][c];
        emb[g * 32 + c] = s / fmaxf((float)(hi - lo), 1.0f);
    }
}

// ---------------------------------------------------------------------------
// Heads: two 32->16->1 MLPs + sigmoid on emb[G,32]. One thread per graph.
// Output layout: out[0:64] = halt, out[64:128] = cont  (reference returns
// (halt, cont)).
// ---------------------------------------------------------------------------
__global__ __launch_bounds__(64) void heads_kernel(
        const float* __restrict__ embg,
        const float* __restrict__ cW1, const float* __restrict__ cb1,
        const float* __restrict__ cW2, const float* __restrict__ cb2,
        const float* __restrict__ hW1, const float* __restrict__ hb1,
        const float* __restrict__ hW2, const float* __restrict__ hb2,
        float* __restrict__ out)
{
    int g = threadIdx.x;
    if (g >= G_GRAPHS) return;
    float emb[32];
    #pragma unroll
    for (int c = 0; c < 32; c++) emb[c] = embg[g * 32 + c];

    // continue head
    float sc = cb2[0];
    #pragma unroll
    for (int j = 0; j < 16; j++) {
        float s = cb1[j];
        #pragma unroll
        for (int c = 0; c < 32; c++) s += emb[c] * cW1[c * 16 + j];
        sc += fmaxf(s, 0.f) * cW2[j];
    }
    float cont = 1.0f / (1.0f + __expf(-sc));

    // halt head
    float sh = hb2[0];
    #pragma unroll
    for (int j = 0; j < 16; j++) {
        float s = hb1[j];
        #pragma unroll
        for (int c = 0; c < 32; c++) s += emb[c] * hW1[c * 16 + j];
        sh += fmaxf(s, 0.f) * hW2[j];
    }
    float halt = 1.0f / (1.0f + __expf(-sh));

    out[g] = halt;
    out[G_GRAPHS + g] = cont;
}

// ---------------------------------------------------------------------------
extern "C" void kernel_launch(void* const* d_in, const int* in_sizes, int n_in,
                              void* d_out, int out_size, void* d_ws, size_t ws_size,
                              hipStream_t stream)
{
    const float* x   = (const float*)d_in[0];
    const int*   ei  = (const int*)  d_in[1];
    const int*   bat = (const int*)  d_in[2];
    const float* W1  = (const float*)d_in[3];
    const float* as1 = (const float*)d_in[4];
    const float* ad1 = (const float*)d_in[5];
    const float* b1  = (const float*)d_in[6];
    const float* W2  = (const float*)d_in[7];
    const float* as2 = (const float*)d_in[8];
    const float* ad2 = (const float*)d_in[9];
    const float* b2  = (const float*)d_in[10];
    const float* cW1 = (const float*)d_in[11];
    const float* cb1 = (const float*)d_in[12];
    const float* cW2 = (const float*)d_in[13];
    const float* cb2 = (const float*)d_in[14];
    const float* hW1 = (const float*)d_in[15];
    const float* hb1 = (const float*)d_in[16];
    const float* hW2 = (const float*)d_in[17];
    const float* hb2 = (const float*)d_in[18];

    const int N    = in_sizes[2];           // 20000
    const int E0   = in_sizes[1] / 2;       // 320000
    const int Etot = E0 + N;                // + self loops
    const int IN   = in_sizes[0] / N;       // 128

    // ---- workspace carve (floats) ----
    float* w = (float*)d_ws;
    size_t o = 0;
    float* h1pre = w + o; o += (size_t)N * 256;   // x@W1  [N,4,64]
    float* a_s1  = w + o; o += (size_t)N * 4;
    float* a_d1  = w + o; o += (size_t)N * 4;
    float* m1    = w + o; o += (size_t)N * 4;
    float* den1  = w + o; o += (size_t)N * 4;
    float* e1    = w + o; o += (size_t)Etot * 4;
    float* agg1  = w + o; o += (size_t)N * 64;    // becomes h1 (in-place relu)
    float* h2pre = w + o; o += (size_t)N * 64;    // h1@W2  [N,2,32]
    float* a_s2  = w + o; o += (size_t)N * 2;
    float* a_d2  = w + o; o += (size_t)N * 2;
    float* m2    = w + o; o += (size_t)N * 2;
    float* den2  = w + o; o += (size_t)N * 2;
    float* e2    = w + o; o += (size_t)Etot * 2;
    float* agg2  = w + o; o += (size_t)N * 32;    // becomes h2 (in-place relu)
    float* emb   = w + o; o += (size_t)G_GRAPHS * 32;
    (void)ws_size; (void)n_in; (void)out_size;

    // ---- init scratch (ws is poisoned 0xAA before every call) ----
    hipMemsetAsync(m1,   0xFF, (size_t)N * 4  * sizeof(float), stream); // -inf-like
    hipMemsetAsync(den1, 0,    (size_t)N * 4  * sizeof(float), stream);
    hipMemsetAsync(agg1, 0,    (size_t)N * 64 * sizeof(float), stream);
    hipMemsetAsync(m2,   0xFF, (size_t)N * 2  * sizeof(float), stream);
    hipMemsetAsync(den2, 0,    (size_t)N * 2  * sizeof(float), stream);
    hipMemsetAsync(agg2, 0,    (size_t)N * 32 * sizeof(float), stream);

    const dim3 blk(256);
    const int eb = (Etot + 255) / 256;

    // ---- layer 1: GAT(128 -> 4 heads x 64, head-mean) + relu ----
    gemm_fp32<<<dim3((N + 63) / 64, 256 / 64), blk, 0, stream>>>(x, W1, h1pre, N, 256, IN);
    att_coef<4, 64><<<(N * 4 + 255) / 256, blk, 0, stream>>>(h1pre, as1, ad1, a_s1, a_d1, N);
    edge_scores<4><<<eb, blk, 0, stream>>>(ei, a_s1, a_d1, e1, m1, E0, Etot);
    edge_exp<4><<<eb, blk, 0, stream>>>(ei, e1, m1, den1, E0, Etot);
    edge_aggregate<4, 64><<<(Etot + 3) / 4, blk, 0, stream>>>(ei, h1pre, e1, den1, agg1, E0, Etot);
    node_finish<64><<<(N * 64 + 255) / 256, blk, 0, stream>>>(agg1, b1, agg1, 0.25f, N);

    // ---- layer 2: GAT(64 -> 2 heads x 32, head-mean) + relu ----
    gemm_fp32<<<dim3((N + 63) / 64, 1), blk, 0, stream>>>(agg1, W2, h2pre, N, 64, 64);
    att_coef<2, 32><<<(N * 2 + 255) / 256, blk, 0, stream>>>(h2pre, as2, ad2, a_s2, a_d2, N);
    edge_scores<2><<<eb, blk, 0, stream>>>(ei, a_s2, a_d2, e2, m2, E0, Etot);
    edge_exp<2><<<eb, blk, 0, stream>>>(ei, e2, m2, den2, E0, Etot);
    edge_aggregate<2, 32><<<(Etot + 7) / 8, blk, 0, stream>>>(ei, h2pre, e2, den2, agg2, E0, Etot);
    node_finish<32><<<(N * 32 + 255) / 256, blk, 0, stream>>>(agg2, b2, agg2, 0.5f, N);

    // ---- pool + heads (no atomics: batch is sorted) ----
    pool_pergraph<<<G_GRAPHS, blk, 0, stream>>>(agg2, bat, emb, N);
    heads_kernel<<<1, 64, 0, stream>>>(emb, cW1, cb1, cW2, cb2,
                                       hW1, hb1, hW2, hb2, (float*)d_out);
}

// Round 3
// 375.911 us; speedup vs baseline: 1.6808x; 1.3179x over previous
//
#include <hip/hip_runtime.h>

// ---------------------------------------------------------------------------
// GAT policy module: 2x GAT layer (head-mean) + mean-pool + 2 MLP heads.
// Round 2: dst-CSR + fused per-node GAT aggregation (no scatter atomics).
//   - CSR built once per call (count -> single-block scan -> fill), reused
//     by both layers (same edge structure).
//   - gat_dst<H,C>: one wave per dst node; pass1 = per-head score max,
//     pass2 = exp/denominator/weighted gather; softmax div + head mean +
//     bias + relu fused in epilogue. Single coalesced write per node.
// ---------------------------------------------------------------------------

#define G_GRAPHS 64

// ---------------------------------------------------------------------------
// fp32 register-tiled GEMM: C[M,N] = A[M,K] @ B[K,N]
// BM=64, BN=64, BK=16, 256 threads, 4x4 accum per thread.
// ---------------------------------------------------------------------------
__global__ __launch_bounds__(256) void gemm_fp32(
        const float* __restrict__ A, const float* __restrict__ B,
        float* __restrict__ C, int M, int N, int K)
{
    constexpr int BM = 64, BN = 64, BK = 16;
    __shared__ float As[BK][BM];   // transposed A tile
    __shared__ float Bs[BK][BN];
    const int tid = threadIdx.x;
    const int tx = tid % 16;
    const int ty = tid / 16;
    const int row0 = blockIdx.x * BM;
    const int col0 = blockIdx.y * BN;

    float acc[4][4] = {};

    for (int kt = 0; kt < K; kt += BK) {
        {
            int r  = tid >> 2;
            int c4 = (tid & 3) * 4;
            int gr = row0 + r;
            float4 v = make_float4(0.f, 0.f, 0.f, 0.f);
            if (gr < M) v = *reinterpret_cast<const float4*>(&A[(size_t)gr * K + kt + c4]);
            As[c4 + 0][r] = v.x; As[c4 + 1][r] = v.y;
            As[c4 + 2][r] = v.z; As[c4 + 3][r] = v.w;
        }
        {
            int r  = tid >> 4;
            int c4 = (tid & 15) * 4;
            float4 v = *reinterpret_cast<const float4*>(&B[(size_t)(kt + r) * N + col0 + c4]);
            *reinterpret_cast<float4*>(&Bs[r][c4]) = v;
        }
        __syncthreads();
        #pragma unroll
        for (int k = 0; k < BK; k++) {
            float ra[4], rb[4];
            #pragma unroll
            for (int i = 0; i < 4; i++) ra[i] = As[k][ty * 4 + i];
            #pragma unroll
            for (int j = 0; j < 4; j++) rb[j] = Bs[k][tx * 4 + j];
            #pragma unroll
            for (int i = 0; i < 4; i++)
                #pragma unroll
                for (int j = 0; j < 4; j++)
                    acc[i][j] += ra[i] * rb[j];
        }
        __syncthreads();
    }

    #pragma unroll
    for (int i = 0; i < 4; i++) {
        int gr = row0 + ty * 4 + i;
        if (gr < M) {
            #pragma unroll
            for (int j = 0; j < 4; j++)
                C[(size_t)gr * N + col0 + tx * 4 + j] = acc[i][j];
        }
    }
}

// ---------------------------------------------------------------------------
// a_src[n,h] = sum_c h[n,h,c]*att_s[h,c] ; a_dst likewise. Thread per (n,h).
// ---------------------------------------------------------------------------
template<int H, int C>
__global__ __launch_bounds__(256) void att_coef(
        const float* __restrict__ hfeat, const float* __restrict__ att_s,
        const float* __restrict__ att_d, float* __restrict__ a_s,
        float* __restrict__ a_d, int N)
{
    int idx = blockIdx.x * 256 + threadIdx.x;
    if (idx >= N * H) return;
    int n = idx / H, h = idx % H;
    const float* hp = hfeat + (size_t)n * (H * C) + h * C;
    const float* as = att_s + h * C;
    const float* ad = att_d + h * C;
    float ss = 0.f, sd = 0.f;
    #pragma unroll 8
    for (int c = 0; c < C; c++) {
        float v = hp[c];
        ss += v * as[c];
        sd += v * ad[c];
    }
    a_s[idx] = ss;
    a_d[idx] = sd;
}

// ---------------------------------------------------------------------------
// CSR build: degree count -> exclusive scan -> bucket fill.
// Edge list = ei[0:E0] (src), ei[E0:2*E0] (dst), plus self-loops idx>=E0.
// ---------------------------------------------------------------------------
__global__ __launch_bounds__(256) void csr_count(
        const int* __restrict__ ei, int* __restrict__ deg, int E0, int Etot)
{
    int idx = blockIdx.x * 256 + threadIdx.x;
    if (idx >= Etot) return;
    int dst = (idx < E0) ? ei[E0 + idx] : (idx - E0);
    atomicAdd(&deg[dst], 1);
}

// Single-block exclusive scan over deg[N] -> rowptr[N+1] and cursor[N].
__global__ __launch_bounds__(1024) void csr_scan(
        const int* __restrict__ deg, int* __restrict__ rowptr,
        int* __restrict__ cursor, int N)
{
    __shared__ int smem[1024];
    __shared__ int carry_s;
    const int tid = threadIdx.x;
    if (tid == 0) carry_s = 0;
    __syncthreads();
    for (int base = 0; base < N; base += 1024) {
        int i = base + tid;
        int v = (i < N) ? deg[i] : 0;
        smem[tid] = v;
        __syncthreads();
        #pragma unroll
        for (int off = 1; off < 1024; off <<= 1) {
            int t = (tid >= off) ? smem[tid - off] : 0;
            __syncthreads();
            smem[tid] += t;
            __syncthreads();
        }
        int incl = smem[tid];
        int c = carry_s;
        if (i < N) { rowptr[i] = c + incl - v; cursor[i] = c + incl - v; }
        __syncthreads();                 // everyone done reading carry_s
        if (tid == 1023) carry_s = c + smem[1023];
        __syncthreads();
    }
    if (tid == 0) rowptr[N] = carry_s;
}

__global__ __launch_bounds__(256) void csr_fill(
        const int* __restrict__ ei, int* __restrict__ cursor,
        int* __restrict__ col, int E0, int Etot)
{
    int idx = blockIdx.x * 256 + threadIdx.x;
    if (idx >= Etot) return;
    int src = (idx < E0) ? ei[idx]      : (idx - E0);
    int dst = (idx < E0) ? ei[E0 + idx] : (idx - E0);
    int pos = atomicAdd(&cursor[dst], 1);
    col[pos] = src;
}

// ---------------------------------------------------------------------------
// Fused GAT aggregation, one wave per dst node. 256 thr = 4 waves/block.
// Lane layout: slot r covers flattened (h,c) position lane + 64*r of the
// H*C feature vector (layer1: H=4,C=64 -> R=4, h=r, c=lane;
//                     layer2: H=2,C=32 -> R=1, h=lane>>5, c=lane&31).
// Pass 1: per-head running max of leaky-relu scores.
// Pass 2: p = exp(e - m); l += p; acc += p * h[src].
// Epilogue: out[d,c] = relu(mean_h(acc_h / l_h) + bias[c]).  No atomics.
// ---------------------------------------------------------------------------
template<int H, int C>
__global__ __launch_bounds__(256) void gat_dst(
        const int* __restrict__ rowptr, const int* __restrict__ colidx,
        const float* __restrict__ hfeat, const float* __restrict__ a_s,
        const float* __restrict__ a_d, const float* __restrict__ bias,
        float* __restrict__ out, int N)
{
    constexpr int R = (H * C) / 64;
    const int lane = threadIdx.x & 63;
    const int d = blockIdx.x * 4 + (threadIdx.x >> 6);
    if (d >= N) return;
    const int lo = rowptr[d], hi = rowptr[d + 1];

    // head index for each slot (compile-time pattern)
    int hr[R];
    #pragma unroll
    for (int r = 0; r < R; r++) hr[r] = (lane + 64 * r) / C;

    float ad[R];
    #pragma unroll
    for (int r = 0; r < R; r++) ad[r] = a_d[d * H + hr[r]];

    // ---- pass 1: per-slot max ----
    float m[R];
    #pragma unroll
    for (int r = 0; r < R; r++) m[r] = -3.0e38f;
    for (int i = lo; i < hi; i++) {
        int s = colidx[i];
        #pragma unroll
        for (int r = 0; r < R; r++) {
            float e = a_s[s * H + hr[r]] + ad[r];
            e = (e > 0.f) ? e : 0.2f * e;
            m[r] = fmaxf(m[r], e);
        }
    }

    // ---- pass 2: exp / denom / weighted gather ----
    float l[R] = {}, acc[R] = {};
    for (int i = lo; i < hi; i++) {
        int s = colidx[i];
        const float* hp = hfeat + (size_t)s * (H * C);
        #pragma unroll
        for (int r = 0; r < R; r++) {
            float e = a_s[s * H + hr[r]] + ad[r];
            e = (e > 0.f) ? e : 0.2f * e;
            float p = __expf(e - m[r]);
            l[r] += p;
            acc[r] += p * hp[lane + 64 * r];
        }
    }

    // ---- epilogue: softmax div + head mean + bias + relu ----
    if constexpr (C == 64) {
        float o = 0.f;
        #pragma unroll
        for (int r = 0; r < R; r++) o += acc[r] / (l[r] + 1e-16f);
        out[(size_t)d * C + lane] = fmaxf(o * (1.0f / H) + bias[lane], 0.f);
    } else {
        // H=2, C=32: lanes 0-31 head0, 32-63 head1; combine across half-waves
        float v = acc[0] / (l[0] + 1e-16f);
        float other = __shfl_xor(v, 32);
        if (lane < 32)
            out[(size_t)d * C + lane] = fmaxf(0.5f * (v + other) + bias[lane], 0.f);
    }
}

// ---------------------------------------------------------------------------
// Global mean pool, one block per graph (batch sorted -> contiguous segments).
// ---------------------------------------------------------------------------
__global__ __launch_bounds__(256) void pool_pergraph(
        const float* __restrict__ h2, const int* __restrict__ batch,
        float* __restrict__ emb, int N)
{
    const int g = blockIdx.x;
    const int c = threadIdx.x & 31;
    const int r = threadIdx.x >> 5;

    __shared__ int bounds[2];
    if (threadIdx.x < 2) {
        int target = g + (int)threadIdx.x;
        int lo = 0, hi = N;
        while (lo < hi) {
            int mid = (lo + hi) >> 1;
            if (batch[mid] < target) lo = mid + 1; else hi = mid;
        }
        bounds[threadIdx.x] = lo;
    }
    __syncthreads();
    const int lo = bounds[0], hi = bounds[1];

    float acc = 0.f;
    for (int n = lo + r; n < hi; n += 8)
        acc += h2[(size_t)n * 32 + c];

    __shared__ float red[8][32];
    red[r][c] = acc;
    __syncthreads();
    if (r == 0) {
        float s = 0.f;
        #pragma unroll
        for (int i = 0; i < 8; i++) s += red[i][c];
        emb[g * 32 + c] = s / fmaxf((float)(hi - lo), 1.0f);
    }
}

// ---------------------------------------------------------------------------
// Heads: two 32->16->1 MLPs + sigmoid. out[0:64]=halt, out[64:128]=cont.
// ---------------------------------------------------------------------------
__global__ __launch_bounds__(64) void heads_kernel(
        const float* __restrict__ embg,
        const float* __restrict__ cW1, const float* __restrict__ cb1,
        const float* __restrict__ cW2, const float* __restrict__ cb2,
        const float* __restrict__ hW1, const float* __restrict__ hb1,
        const float* __restrict__ hW2, const float* __restrict__ hb2,
        float* __restrict__ out)
{
    int g = threadIdx.x;
    if (g >= G_GRAPHS) return;
    float emb[32];
    #pragma unroll
    for (int c = 0; c < 32; c++) emb[c] = embg[g * 32 + c];

    float sc = cb2[0];
    #pragma unroll
    for (int j = 0; j < 16; j++) {
        float s = cb1[j];
        #pragma unroll
        for (int c = 0; c < 32; c++) s += emb[c] * cW1[c * 16 + j];
        sc += fmaxf(s, 0.f) * cW2[j];
    }
    float cont = 1.0f / (1.0f + __expf(-sc));

    float sh = hb2[0];
    #pragma unroll
    for (int j = 0; j < 16; j++) {
        float s = hb1[j];
        #pragma unroll
        for (int c = 0; c < 32; c++) s += emb[c] * hW1[c * 16 + j];
        sh += fmaxf(s, 0.f) * hW2[j];
    }
    float halt = 1.0f / (1.0f + __expf(-sh));

    out[g] = halt;
    out[G_GRAPHS + g] = cont;
}

// ---------------------------------------------------------------------------
extern "C" void kernel_launch(void* const* d_in, const int* in_sizes, int n_in,
                              void* d_out, int out_size, void* d_ws, size_t ws_size,
                              hipStream_t stream)
{
    const float* x   = (const float*)d_in[0];
    const int*   ei  = (const int*)  d_in[1];
    const int*   bat = (const int*)  d_in[2];
    const float* W1  = (const float*)d_in[3];
    const float* as1 = (const float*)d_in[4];
    const float* ad1 = (const float*)d_in[5];
    const float* b1  = (const float*)d_in[6];
    const float* W2  = (const float*)d_in[7];
    const float* as2 = (const float*)d_in[8];
    const float* ad2 = (const float*)d_in[9];
    const float* b2  = (const float*)d_in[10];
    const float* cW1 = (const float*)d_in[11];
    const float* cb1 = (const float*)d_in[12];
    const float* cW2 = (const float*)d_in[13];
    const float* cb2 = (const float*)d_in[14];
    const float* hW1 = (const float*)d_in[15];
    const float* hb1 = (const float*)d_in[16];
    const float* hW2 = (const float*)d_in[17];
    const float* hb2 = (const float*)d_in[18];

    const int N    = in_sizes[2];           // 20000
    const int E0   = in_sizes[1] / 2;       // 320000
    const int Etot = E0 + N;                // + self loops
    const int IN   = in_sizes[0] / N;       // 128

    // ---- workspace carve ----
    float* w = (float*)d_ws;
    size_t o = 0;
    float* h1pre = w + o; o += (size_t)N * 256;   // x@W1  [N,4,64]
    float* a_s1  = w + o; o += (size_t)N * 4;
    float* a_d1  = w + o; o += (size_t)N * 4;
    float* h1    = w + o; o += (size_t)N * 64;
    float* h2pre = w + o; o += (size_t)N * 64;    // h1@W2  [N,2,32]
    float* a_s2  = w + o; o += (size_t)N * 2;
    float* a_d2  = w + o; o += (size_t)N * 2;
    float* h2    = w + o; o += (size_t)N * 32;
    float* emb   = w + o; o += (size_t)G_GRAPHS * 32;
    int* rowptr  = (int*)(w + o); o += (size_t)N + 1;
    int* cursor  = (int*)(w + o); o += (size_t)N;
    int* deg     = (int*)(w + o); o += (size_t)N;
    int* colidx  = (int*)(w + o); o += (size_t)Etot;
    (void)ws_size; (void)n_in; (void)out_size;

    const dim3 blk(256);
    const int eb = (Etot + 255) / 256;
    const int nb4 = (N + 3) / 4;

    // ---- CSR build (once; shared by both layers) ----
    hipMemsetAsync(deg, 0, (size_t)N * sizeof(int), stream);
    csr_count<<<eb, blk, 0, stream>>>(ei, deg, E0, Etot);
    csr_scan<<<1, 1024, 0, stream>>>(deg, rowptr, cursor, N);
    csr_fill<<<eb, blk, 0, stream>>>(ei, cursor, colidx, E0, Etot);

    // ---- layer 1: GAT(128 -> 4 heads x 64, head-mean) + relu ----
    gemm_fp32<<<dim3((N + 63) / 64, 256 / 64), blk, 0, stream>>>(x, W1, h1pre, N, 256, IN);
    att_coef<4, 64><<<(N * 4 + 255) / 256, blk, 0, stream>>>(h1pre, as1, ad1, a_s1, a_d1, N);
    gat_dst<4, 64><<<nb4, blk, 0, stream>>>(rowptr, colidx, h1pre, a_s1, a_d1, b1, h1, N);

    // ---- layer 2: GAT(64 -> 2 heads x 32, head-mean) + relu ----
    gemm_fp32<<<dim3((N + 63) / 64, 1), blk, 0, stream>>>(h1, W2, h2pre, N, 64, 64);
    att_coef<2, 32><<<(N * 2 + 255) / 256, blk, 0, stream>>>(h2pre, as2, ad2, a_s2, a_d2, N);
    gat_dst<2, 32><<<nb4, blk, 0, stream>>>(rowptr, colidx, h2pre, a_s2, a_d2, b2, h2, N);

    // ---- pool + heads (no atomics: batch is sorted) ----
    pool_pergraph<<<G_GRAPHS, blk, 0, stream>>>(h2, bat, emb, N);
    heads_kernel<<<1, 64, 0, stream>>>(emb, cW1, cb1, cW2, cb2,
                                       hW1, hb1, hW2, hb2, (float*)d_out);
}

// Round 4
// 316.510 us; speedup vs baseline: 1.9963x; 1.1877x over previous
//
#include <hip/hip_runtime.h>

// ---------------------------------------------------------------------------
// GAT policy module: 2x GAT layer (head-mean) + mean-pool + 2 MLP heads.
// Round 3: gat_dst restructured — lane-parallel score/max/exp phase,
// float4 feature gather (1 dwordx4/edge), p staged in per-wave LDS,
// shuffle reductions. ~5x fewer wave-instructions per edge.
// ---------------------------------------------------------------------------

#define G_GRAPHS 64

// ---------------------------------------------------------------------------
// fp32 register-tiled GEMM: C[M,N] = A[M,K] @ B[K,N]
// ---------------------------------------------------------------------------
__global__ __launch_bounds__(256) void gemm_fp32(
        const float* __restrict__ A, const float* __restrict__ B,
        float* __restrict__ C, int M, int N, int K)
{
    constexpr int BM = 64, BN = 64, BK = 16;
    __shared__ float As[BK][BM];
    __shared__ float Bs[BK][BN];
    const int tid = threadIdx.x;
    const int tx = tid % 16;
    const int ty = tid / 16;
    const int row0 = blockIdx.x * BM;
    const int col0 = blockIdx.y * BN;

    float acc[4][4] = {};

    for (int kt = 0; kt < K; kt += BK) {
        {
            int r  = tid >> 2;
            int c4 = (tid & 3) * 4;
            int gr = row0 + r;
            float4 v = make_float4(0.f, 0.f, 0.f, 0.f);
            if (gr < M) v = *reinterpret_cast<const float4*>(&A[(size_t)gr * K + kt + c4]);
            As[c4 + 0][r] = v.x; As[c4 + 1][r] = v.y;
            As[c4 + 2][r] = v.z; As[c4 + 3][r] = v.w;
        }
        {
            int r  = tid >> 4;
            int c4 = (tid & 15) * 4;
            float4 v = *reinterpret_cast<const float4*>(&B[(size_t)(kt + r) * N + col0 + c4]);
            *reinterpret_cast<float4*>(&Bs[r][c4]) = v;
        }
        __syncthreads();
        #pragma unroll
        for (int k = 0; k < BK; k++) {
            float ra[4], rb[4];
            #pragma unroll
            for (int i = 0; i < 4; i++) ra[i] = As[k][ty * 4 + i];
            #pragma unroll
            for (int j = 0; j < 4; j++) rb[j] = Bs[k][tx * 4 + j];
            #pragma unroll
            for (int i = 0; i < 4; i++)
                #pragma unroll
                for (int j = 0; j < 4; j++)
                    acc[i][j] += ra[i] * rb[j];
        }
        __syncthreads();
    }

    #pragma unroll
    for (int i = 0; i < 4; i++) {
        int gr = row0 + ty * 4 + i;
        if (gr < M) {
            #pragma unroll
            for (int j = 0; j < 4; j++)
                C[(size_t)gr * N + col0 + tx * 4 + j] = acc[i][j];
        }
    }
}

// ---------------------------------------------------------------------------
// a_src[n,h] = sum_c h[n,h,c]*att_s[h,c] ; a_dst likewise. Thread per (n,h).
// ---------------------------------------------------------------------------
template<int H, int C>
__global__ __launch_bounds__(256) void att_coef(
        const float* __restrict__ hfeat, const float* __restrict__ att_s,
        const float* __restrict__ att_d, float* __restrict__ a_s,
        float* __restrict__ a_d, int N)
{
    int idx = blockIdx.x * 256 + threadIdx.x;
    if (idx >= N * H) return;
    int n = idx / H, h = idx % H;
    const float* hp = hfeat + (size_t)n * (H * C) + h * C;
    const float* as = att_s + h * C;
    const float* ad = att_d + h * C;
    float ss = 0.f, sd = 0.f;
    #pragma unroll 8
    for (int c = 0; c < C; c++) {
        float v = hp[c];
        ss += v * as[c];
        sd += v * ad[c];
    }
    a_s[idx] = ss;
    a_d[idx] = sd;
}

// ---------------------------------------------------------------------------
// CSR build: degree count -> exclusive scan -> bucket fill.
// ---------------------------------------------------------------------------
__global__ __launch_bounds__(256) void csr_count(
        const int* __restrict__ ei, int* __restrict__ deg, int E0, int Etot)
{
    int idx = blockIdx.x * 256 + threadIdx.x;
    if (idx >= Etot) return;
    int dst = (idx < E0) ? ei[E0 + idx] : (idx - E0);
    atomicAdd(&deg[dst], 1);
}

__global__ __launch_bounds__(1024) void csr_scan(
        const int* __restrict__ deg, int* __restrict__ rowptr,
        int* __restrict__ cursor, int N)
{
    __shared__ int smem[1024];
    __shared__ int carry_s;
    const int tid = threadIdx.x;
    if (tid == 0) carry_s = 0;
    __syncthreads();
    for (int base = 0; base < N; base += 1024) {
        int i = base + tid;
        int v = (i < N) ? deg[i] : 0;
        smem[tid] = v;
        __syncthreads();
        #pragma unroll
        for (int off = 1; off < 1024; off <<= 1) {
            int t = (tid >= off) ? smem[tid - off] : 0;
            __syncthreads();
            smem[tid] += t;
            __syncthreads();
        }
        int incl = smem[tid];
        int c = carry_s;
        if (i < N) { rowptr[i] = c + incl - v; cursor[i] = c + incl - v; }
        __syncthreads();
        if (tid == 1023) carry_s = c + smem[1023];
        __syncthreads();
    }
    if (tid == 0) rowptr[N] = carry_s;
}

__global__ __launch_bounds__(256) void csr_fill(
        const int* __restrict__ ei, int* __restrict__ cursor,
        int* __restrict__ col, int E0, int Etot)
{
    int idx = blockIdx.x * 256 + threadIdx.x;
    if (idx >= Etot) return;
    int src = (idx < E0) ? ei[idx]      : (idx - E0);
    int dst = (idx < E0) ? ei[E0 + idx] : (idx - E0);
    int pos = atomicAdd(&cursor[dst], 1);
    col[pos] = src;
}

// ---------------------------------------------------------------------------
// Fused GAT aggregation, one wave per dst node. 256 thr = 4 waves/block.
// Feature layout: lane holds channels [lane*FV, lane*FV+FV) of the flat
// H*C row (FV = H*C/64). For both layers each lane's FV channels sit in a
// single head: h_lane = lane*FV / C.
//  Phase 1 (lane-parallel over edges): coalesced colidx read, vector a_s
//    gather, leaky-relu scores; shfl_xor max-reduce per head.
//  Phase 2 (lane-parallel): p=exp(e-m) (one exp per edge per head ACROSS
//    the wave), denom in registers + shfl reduce; p staged in per-wave LDS.
//  Phase 3 (serial over edges): s_j via __shfl (readlane), p via LDS
//    broadcast, one global dwordx4 (FV=4) / dword (FV=1) per edge, FMA.
//  Epilogue: softmax div + head-mean via shfl_xor(16/32) + bias + relu,
//    single vector store. No atomics anywhere.
// ---------------------------------------------------------------------------
template<int H, int C>
__global__ __launch_bounds__(256) void gat_dst(
        const int* __restrict__ rowptr, const int* __restrict__ colidx,
        const float* __restrict__ hfeat, const float* __restrict__ a_s,
        const float* __restrict__ a_d, const float* __restrict__ bias,
        float* __restrict__ out, int N)
{
    constexpr int FV = (H * C) / 64;     // floats per lane (L1: 4, L2: 1)
    const int wid  = threadIdx.x >> 6;
    const int lane = threadIdx.x & 63;
    const int d = blockIdx.x * 4 + wid;

    __shared__ float p_sh[4][64 * H];

    if (d >= N) return;
    const int lo = rowptr[d], hi = rowptr[d + 1];
    const int deg = hi - lo;
    const int h_lane = (lane * FV) / C;

    float adp[H];
    #pragma unroll
    for (int h = 0; h < H; h++) adp[h] = a_d[d * H + h];

    float lh[H];
    #pragma unroll
    for (int h = 0; h < H; h++) lh[h] = 0.f;
    float acc[FV];
    #pragma unroll
    for (int v = 0; v < FV; v++) acc[v] = 0.f;

    if (deg <= 64) {
        // ---------------- fast path: one chunk, scores stay in regs -------
        int s = 0;
        float e[H];
        const bool valid = lane < deg;
        if (valid) {
            s = colidx[lo + lane];
            #pragma unroll
            for (int h = 0; h < H; h++) {
                float v = a_s[s * H + h] + adp[h];
                e[h] = (v > 0.f) ? v : 0.2f * v;
            }
        } else {
            #pragma unroll
            for (int h = 0; h < H; h++) e[h] = -3.0e38f;
        }
        float mh[H];
        #pragma unroll
        for (int h = 0; h < H; h++) mh[h] = e[h];
        #pragma unroll
        for (int off = 1; off < 64; off <<= 1)
            #pragma unroll
            for (int h = 0; h < H; h++)
                mh[h] = fmaxf(mh[h], __shfl_xor(mh[h], off));

        if (valid) {
            #pragma unroll
            for (int h = 0; h < H; h++) {
                float p = __expf(e[h] - mh[h]);
                lh[h] = p;
                p_sh[wid][lane * H + h] = p;
            }
        }
        #pragma unroll
        for (int off = 1; off < 64; off <<= 1)
            #pragma unroll
            for (int h = 0; h < H; h++)
                lh[h] += __shfl_xor(lh[h], off);

        for (int j = 0; j < deg; j++) {
            int s_j = __shfl(s, j);
            float pj = p_sh[wid][j * H + h_lane];
            const float* hp = hfeat + (size_t)s_j * (H * C) + lane * FV;
            if constexpr (FV == 4) {
                float4 f = *reinterpret_cast<const float4*>(hp);
                acc[0] += pj * f.x; acc[1] += pj * f.y;
                acc[2] += pj * f.z; acc[3] += pj * f.w;
            } else {
                acc[0] += pj * hp[0];
            }
        }
    } else {
        // ---------------- general path (deg > 64, rare) -------------------
        float mh[H];
        #pragma unroll
        for (int h = 0; h < H; h++) mh[h] = -3.0e38f;
        for (int i = lo + lane; i < hi; i += 64) {
            int s = colidx[i];
            #pragma unroll
            for (int h = 0; h < H; h++) {
                float v = a_s[s * H + h] + adp[h];
                v = (v > 0.f) ? v : 0.2f * v;
                mh[h] = fmaxf(mh[h], v);
            }
        }
        #pragma unroll
        for (int off = 1; off < 64; off <<= 1)
            #pragma unroll
            for (int h = 0; h < H; h++)
                mh[h] = fmaxf(mh[h], __shfl_xor(mh[h], off));

        for (int base = lo; base < hi; base += 64) {
            int i = base + lane;
            int s = 0;
            if (i < hi) {
                s = colidx[i];
                #pragma unroll
                for (int h = 0; h < H; h++) {
                    float v = a_s[s * H + h] + adp[h];
                    v = (v > 0.f) ? v : 0.2f * v;
                    float p = __expf(v - mh[h]);
                    lh[h] += p;
                    p_sh[wid][(i - base) * H + h] = p;
                }
            }
            int cnt = min(64, hi - base);
            for (int j = 0; j < cnt; j++) {
                int s_j = __shfl(s, j);
                float pj = p_sh[wid][j * H + h_lane];
                const float* hp = hfeat + (size_t)s_j * (H * C) + lane * FV;
                if constexpr (FV == 4) {
                    float4 f = *reinterpret_cast<const float4*>(hp);
                    acc[0] += pj * f.x; acc[1] += pj * f.y;
                    acc[2] += pj * f.z; acc[3] += pj * f.w;
                } else {
                    acc[0] += pj * hp[0];
                }
            }
        }
        #pragma unroll
        for (int off = 1; off < 64; off <<= 1)
            #pragma unroll
            for (int h = 0; h < H; h++)
                lh[h] += __shfl_xor(lh[h], off);
    }

    // ---------------- epilogue ----------------
    float lsel = lh[0];
    #pragma unroll
    for (int h = 1; h < H; h++) if (h_lane == h) lsel = lh[h];
    const float inv = 1.0f / (lsel + 1e-16f);

    if constexpr (FV == 4) {           // H=4, C=64
        float vx = acc[0] * inv, vy = acc[1] * inv,
              vz = acc[2] * inv, vw = acc[3] * inv;
        vx += __shfl_xor(vx, 16); vy += __shfl_xor(vy, 16);
        vz += __shfl_xor(vz, 16); vw += __shfl_xor(vw, 16);
        vx += __shfl_xor(vx, 32); vy += __shfl_xor(vy, 32);
        vz += __shfl_xor(vz, 32); vw += __shfl_xor(vw, 32);
        if (lane < 16) {
            float4 bv = *reinterpret_cast<const float4*>(&bias[lane * 4]);
            float4 o;
            o.x = fmaxf(0.25f * vx + bv.x, 0.f);
            o.y = fmaxf(0.25f * vy + bv.y, 0.f);
            o.z = fmaxf(0.25f * vz + bv.z, 0.f);
            o.w = fmaxf(0.25f * vw + bv.w, 0.f);
            *reinterpret_cast<float4*>(&out[(size_t)d * C + lane * 4]) = o;
        }
    } else {                           // H=2, C=32
        float v = acc[0] * inv;
        v += __shfl_xor(v, 32);
        if (lane < 32)
            out[(size_t)d * C + lane] = fmaxf(0.5f * v + bias[lane], 0.f);
    }
}

// ---------------------------------------------------------------------------
// Global mean pool, one block per graph (batch sorted -> contiguous segments).
// ---------------------------------------------------------------------------
__global__ __launch_bounds__(256) void pool_pergraph(
        const float* __restrict__ h2, const int* __restrict__ batch,
        float* __restrict__ emb, int N)
{
    const int g = blockIdx.x;
    const int c = threadIdx.x & 31;
    const int r = threadIdx.x >> 5;

    __shared__ int bounds[2];
    if (threadIdx.x < 2) {
        int target = g + (int)threadIdx.x;
        int lo = 0, hi = N;
        while (lo < hi) {
            int mid = (lo + hi) >> 1;
            if (batch[mid] < target) lo = mid + 1; else hi = mid;
        }
        bounds[threadIdx.x] = lo;
    }
    __syncthreads();
    const int lo = bounds[0], hi = bounds[1];

    float acc = 0.f;
    for (int n = lo + r; n < hi; n += 8)
        acc += h2[(size_t)n * 32 + c];

    __shared__ float red[8][32];
    red[r][c] = acc;
    __syncthreads();
    if (r == 0) {
        float s = 0.f;
        #pragma unroll
        for (int i = 0; i < 8; i++) s += red[i][c];
        emb[g * 32 + c] = s / fmaxf((float)(hi - lo), 1.0f);
    }
}

// ---------------------------------------------------------------------------
// Heads: two 32->16->1 MLPs + sigmoid. out[0:64]=halt, out[64:128]=cont.
// ---------------------------------------------------------------------------
__global__ __launch_bounds__(64) void heads_kernel(
        const float* __restrict__ embg,
        const float* __restrict__ cW1, const float* __restrict__ cb1,
        const float* __restrict__ cW2, const float* __restrict__ cb2,
        const float* __restrict__ hW1, const float* __restrict__ hb1,
        const float* __restrict__ hW2, const float* __restrict__ hb2,
        float* __restrict__ out)
{
    int g = threadIdx.x;
    if (g >= G_GRAPHS) return;
    float emb[32];
    #pragma unroll
    for (int c = 0; c < 32; c++) emb[c] = embg[g * 32 + c];

    float sc = cb2[0];
    #pragma unroll
    for (int j = 0; j < 16; j++) {
        float s = cb1[j];
        #pragma unroll
        for (int c = 0; c < 32; c++) s += emb[c] * cW1[c * 16 + j];
        sc += fmaxf(s, 0.f) * cW2[j];
    }
    float cont = 1.0f / (1.0f + __expf(-sc));

    float sh = hb2[0];
    #pragma unroll
    for (int j = 0; j < 16; j++) {
        float s = hb1[j];
        #pragma unroll
        for (int c = 0; c < 32; c++) s += emb[c] * hW1[c * 16 + j];
        sh += fmaxf(s, 0.f) * hW2[j];
    }
    float halt = 1.0f / (1.0f + __expf(-sh));

    out[g] = halt;
    out[G_GRAPHS + g] = cont;
}

// ---------------------------------------------------------------------------
extern "C" void kernel_launch(void* const* d_in, const int* in_sizes, int n_in,
                              void* d_out, int out_size, void* d_ws, size_t ws_size,
                              hipStream_t stream)
{
    const float* x   = (const float*)d_in[0];
    const int*   ei  = (const int*)  d_in[1];
    const int*   bat = (const int*)  d_in[2];
    const float* W1  = (const float*)d_in[3];
    const float* as1 = (const float*)d_in[4];
    const float* ad1 = (const float*)d_in[5];
    const float* b1  = (const float*)d_in[6];
    const float* W2  = (const float*)d_in[7];
    const float* as2 = (const float*)d_in[8];
    const float* ad2 = (const float*)d_in[9];
    const float* b2  = (const float*)d_in[10];
    const float* cW1 = (const float*)d_in[11];
    const float* cb1 = (const float*)d_in[12];
    const float* cW2 = (const float*)d_in[13];
    const float* cb2 = (const float*)d_in[14];
    const float* hW1 = (const float*)d_in[15];
    const float* hb1 = (const float*)d_in[16];
    const float* hW2 = (const float*)d_in[17];
    const float* hb2 = (const float*)d_in[18];

    const int N    = in_sizes[2];           // 20000
    const int E0   = in_sizes[1] / 2;       // 320000
    const int Etot = E0 + N;                // + self loops
    const int IN   = in_sizes[0] / N;       // 128

    // ---- workspace carve ----
    float* w = (float*)d_ws;
    size_t o = 0;
    float* h1pre = w + o; o += (size_t)N * 256;   // x@W1  [N,4,64]
    float* a_s1  = w + o; o += (size_t)N * 4;
    float* a_d1  = w + o; o += (size_t)N * 4;
    float* h1    = w + o; o += (size_t)N * 64;
    float* h2pre = w + o; o += (size_t)N * 64;    // h1@W2  [N,2,32]
    float* a_s2  = w + o; o += (size_t)N * 2;
    float* a_d2  = w + o; o += (size_t)N * 2;
    float* h2    = w + o; o += (size_t)N * 32;
    float* emb   = w + o; o += (size_t)G_GRAPHS * 32;
    int* rowptr  = (int*)(w + o); o += (size_t)N + 1;
    int* cursor  = (int*)(w + o); o += (size_t)N;
    int* deg     = (int*)(w + o); o += (size_t)N;
    int* colidx  = (int*)(w + o); o += (size_t)Etot;
    (void)ws_size; (void)n_in; (void)out_size;

    const dim3 blk(256);
    const int eb = (Etot + 255) / 256;
    const int nb4 = (N + 3) / 4;

    // ---- CSR build (once; shared by both layers) ----
    hipMemsetAsync(deg, 0, (size_t)N * sizeof(int), stream);
    csr_count<<<eb, blk, 0, stream>>>(ei, deg, E0, Etot);
    csr_scan<<<1, 1024, 0, stream>>>(deg, rowptr, cursor, N);
    csr_fill<<<eb, blk, 0, stream>>>(ei, cursor, colidx, E0, Etot);

    // ---- layer 1: GAT(128 -> 4 heads x 64, head-mean) + relu ----
    gemm_fp32<<<dim3((N + 63) / 64, 256 / 64), blk, 0, stream>>>(x, W1, h1pre, N, 256, IN);
    att_coef<4, 64><<<(N * 4 + 255) / 256, blk, 0, stream>>>(h1pre, as1, ad1, a_s1, a_d1, N);
    gat_dst<4, 64><<<nb4, blk, 0, stream>>>(rowptr, colidx, h1pre, a_s1, a_d1, b1, h1, N);

    // ---- layer 2: GAT(64 -> 2 heads x 32, head-mean) + relu ----
    gemm_fp32<<<dim3((N + 63) / 64, 1), blk, 0, stream>>>(h1, W2, h2pre, N, 64, 64);
    att_coef<2, 32><<<(N * 2 + 255) / 256, blk, 0, stream>>>(h2pre, as2, ad2, a_s2, a_d2, N);
    gat_dst<2, 32><<<nb4, blk, 0, stream>>>(rowptr, colidx, h2pre, a_s2, a_d2, b2, h2, N);

    // ---- pool + heads (no atomics: batch is sorted) ----
    pool_pergraph<<<G_GRAPHS, blk, 0, stream>>>(h2, bat, emb, N);
    heads_kernel<<<1, 64, 0, stream>>>(emb, cW1, cb1, cW2, cb2,
                                       hW1, hb1, hW2, hb2, (float*)d_out);
}

// Round 5
// 272.667 us; speedup vs baseline: 2.3172x; 1.1608x over previous
//
#include <hip/hip_runtime.h>
#include <hip/hip_fp16.h>

// ---------------------------------------------------------------------------
// GAT policy module: 2x GAT layer (head-mean) + mean-pool + 2 MLP heads.
// Round 4: fp16 feature path (halves gather/store bytes), 4-deep unrolled
// gather (4 loads in flight; phase 3 was 1-load-at-a-time latency-bound),
// single-chunk csr_scan (old one ran 20 serial block-scans on one CU).
// ---------------------------------------------------------------------------

#define G_GRAPHS 64

// ---------------------------------------------------------------------------
// fp32 register-tiled GEMM: C[M,N] = A[M,K] @ B[K,N], fp16 output.
// BM=64, BN=64, BK=16, 256 threads, 4x4 accum per thread.
// ---------------------------------------------------------------------------
__global__ __launch_bounds__(256) void gemm_fp32(
        const float* __restrict__ A, const float* __restrict__ B,
        __half* __restrict__ Ch, int M, int N, int K)
{
    constexpr int BM = 64, BN = 64, BK = 16;
    __shared__ float As[BK][BM];
    __shared__ float Bs[BK][BN];
    const int tid = threadIdx.x;
    const int tx = tid % 16;
    const int ty = tid / 16;
    const int row0 = blockIdx.x * BM;
    const int col0 = blockIdx.y * BN;

    float acc[4][4] = {};

    for (int kt = 0; kt < K; kt += BK) {
        {
            int r  = tid >> 2;
            int c4 = (tid & 3) * 4;
            int gr = row0 + r;
            float4 v = make_float4(0.f, 0.f, 0.f, 0.f);
            if (gr < M) v = *reinterpret_cast<const float4*>(&A[(size_t)gr * K + kt + c4]);
            As[c4 + 0][r] = v.x; As[c4 + 1][r] = v.y;
            As[c4 + 2][r] = v.z; As[c4 + 3][r] = v.w;
        }
        {
            int r  = tid >> 4;
            int c4 = (tid & 15) * 4;
            float4 v = *reinterpret_cast<const float4*>(&B[(size_t)(kt + r) * N + col0 + c4]);
            *reinterpret_cast<float4*>(&Bs[r][c4]) = v;
        }
        __syncthreads();
        #pragma unroll
        for (int k = 0; k < BK; k++) {
            float ra[4], rb[4];
            #pragma unroll
            for (int i = 0; i < 4; i++) ra[i] = As[k][ty * 4 + i];
            #pragma unroll
            for (int j = 0; j < 4; j++) rb[j] = Bs[k][tx * 4 + j];
            #pragma unroll
            for (int i = 0; i < 4; i++)
                #pragma unroll
                for (int j = 0; j < 4; j++)
                    acc[i][j] += ra[i] * rb[j];
        }
        __syncthreads();
    }

    #pragma unroll
    for (int i = 0; i < 4; i++) {
        int gr = row0 + ty * 4 + i;
        if (gr < M) {
            __half2 lo = __floats2half2_rn(acc[i][0], acc[i][1]);
            __half2 hi = __floats2half2_rn(acc[i][2], acc[i][3]);
            __half2* dst = reinterpret_cast<__half2*>(&Ch[(size_t)gr * N + col0 + tx * 4]);
            dst[0] = lo; dst[1] = hi;
        }
    }
}

// ---------------------------------------------------------------------------
// a_src[n,h] = sum_c h[n,h,c]*att_s[h,c] (fp16 features). Thread per (n,h).
// ---------------------------------------------------------------------------
template<int H, int C>
__global__ __launch_bounds__(256) void att_coef(
        const __half* __restrict__ hfeat, const float* __restrict__ att_s,
        const float* __restrict__ att_d, float* __restrict__ a_s,
        float* __restrict__ a_d, int N)
{
    int idx = blockIdx.x * 256 + threadIdx.x;
    if (idx >= N * H) return;
    int n = idx / H, h = idx % H;
    const __half2* hp2 = reinterpret_cast<const __half2*>(
        hfeat + (size_t)n * (H * C) + h * C);
    const float* as = att_s + h * C;
    const float* ad = att_d + h * C;
    float ss = 0.f, sd = 0.f;
    #pragma unroll 8
    for (int c2 = 0; c2 < C / 2; c2++) {
        float2 f = __half22float2(hp2[c2]);
        ss += f.x * as[2 * c2] + f.y * as[2 * c2 + 1];
        sd += f.x * ad[2 * c2] + f.y * ad[2 * c2 + 1];
    }
    a_s[idx] = ss;
    a_d[idx] = sd;
}

// ---------------------------------------------------------------------------
// CSR build: degree count -> exclusive scan -> bucket fill.
// ---------------------------------------------------------------------------
__global__ __launch_bounds__(256) void csr_count(
        const int* __restrict__ ei, int* __restrict__ deg, int E0, int Etot)
{
    int idx = blockIdx.x * 256 + threadIdx.x;
    if (idx >= Etot) return;
    int dst = (idx < E0) ? ei[E0 + idx] : (idx - E0);
    atomicAdd(&deg[dst], 1);
}

// Single-chunk scan: thread t owns items [t*I, t*I+I); serial local sum,
// one 1024-wide block scan, serial prefix write-out. One kernel, one pass.
__global__ __launch_bounds__(1024) void csr_scan(
        const int* __restrict__ deg, int* __restrict__ rowptr,
        int* __restrict__ cursor, int N)
{
    const int tid = threadIdx.x;
    const int items = (N + 1023) >> 10;
    const int b = tid * items;
    int sum = 0;
    for (int k = 0; k < items; k++) {
        int i = b + k;
        sum += (i < N) ? deg[i] : 0;
    }
    __shared__ int smem[1024];
    smem[tid] = sum;
    __syncthreads();
    for (int off = 1; off < 1024; off <<= 1) {
        int t = (tid >= off) ? smem[tid - off] : 0;
        __syncthreads();
        smem[tid] += t;
        __syncthreads();
    }
    int excl = smem[tid] - sum;          // exclusive prefix of this chunk
    for (int k = 0; k < items; k++) {
        int i = b + k;
        if (i < N) {
            rowptr[i] = excl; cursor[i] = excl;
            excl += deg[i];
        }
    }
    if (tid == 1023) rowptr[N] = excl;   // grand total
}

__global__ __launch_bounds__(256) void csr_fill(
        const int* __restrict__ ei, int* __restrict__ cursor,
        int* __restrict__ col, int E0, int Etot)
{
    int idx = blockIdx.x * 256 + threadIdx.x;
    if (idx >= Etot) return;
    int src = (idx < E0) ? ei[idx]      : (idx - E0);
    int dst = (idx < E0) ? ei[E0 + idx] : (idx - E0);
    int pos = atomicAdd(&cursor[dst], 1);
    col[pos] = src;
}

// ---------------------------------------------------------------------------
// fp16 gather helper: 8B load = 4 halves; FMA into 4-float acc.
// ---------------------------------------------------------------------------
__device__ inline void gacc4(float* a, const __half* hp, float p) {
    float2 raw = *reinterpret_cast<const float2*>(hp);   // one dwordx2
    __half2 h0 = *reinterpret_cast<__half2*>(&raw.x);
    __half2 h1 = *reinterpret_cast<__half2*>(&raw.y);
    float2 f0 = __half22float2(h0), f1 = __half22float2(h1);
    a[0] += p * f0.x; a[1] += p * f0.y; a[2] += p * f1.x; a[3] += p * f1.y;
}

// ---------------------------------------------------------------------------
// Fused GAT aggregation, one wave per dst node. 256 thr = 4 waves/block.
// fp16 features; 4-deep unrolled gather with 4 independent accumulators.
// ---------------------------------------------------------------------------
template<int H, int C>
__global__ __launch_bounds__(256) void gat_dst(
        const int* __restrict__ rowptr, const int* __restrict__ colidx,
        const __half* __restrict__ hfeat, const float* __restrict__ a_s,
        const float* __restrict__ a_d, const float* __restrict__ bias,
        float* __restrict__ out, int N)
{
    constexpr int FV = (H * C) / 64;     // feature elems per lane (L1:4, L2:1)
    const int wid  = threadIdx.x >> 6;
    const int lane = threadIdx.x & 63;
    const int d = blockIdx.x * 4 + wid;

    __shared__ float p_sh[4][64 * H];

    if (d >= N) return;
    const int lo = rowptr[d], hi = rowptr[d + 1];
    const int deg = hi - lo;
    const int h_lane = (lane * FV) / C;

    float adp[H];
    #pragma unroll
    for (int h = 0; h < H; h++) adp[h] = a_d[d * H + h];

    float lh[H];
    #pragma unroll
    for (int h = 0; h < H; h++) lh[h] = 0.f;
    float acc[FV];
    #pragma unroll
    for (int v = 0; v < FV; v++) acc[v] = 0.f;

    if (deg <= 64) {
        // ---------------- fast path: one chunk, scores stay in regs -------
        int s = 0;
        float e[H];
        const bool valid = lane < deg;
        if (valid) {
            s = colidx[lo + lane];
            if constexpr (H == 4) {
                float4 av = *reinterpret_cast<const float4*>(&a_s[s * 4]);
                float ev[4] = {av.x + adp[0], av.y + adp[1],
                               av.z + adp[2], av.w + adp[3]};
                #pragma unroll
                for (int h = 0; h < 4; h++)
                    e[h] = (ev[h] > 0.f) ? ev[h] : 0.2f * ev[h];
            } else {
                float2 av = *reinterpret_cast<const float2*>(&a_s[s * 2]);
                float ev[2] = {av.x + adp[0], av.y + adp[1]};
                #pragma unroll
                for (int h = 0; h < 2; h++)
                    e[h] = (ev[h] > 0.f) ? ev[h] : 0.2f * ev[h];
            }
        } else {
            #pragma unroll
            for (int h = 0; h < H; h++) e[h] = -3.0e38f;
        }
        float mh[H];
        #pragma unroll
        for (int h = 0; h < H; h++) mh[h] = e[h];
        #pragma unroll
        for (int off = 1; off < 64; off <<= 1)
            #pragma unroll
            for (int h = 0; h < H; h++)
                mh[h] = fmaxf(mh[h], __shfl_xor(mh[h], off));

        if (valid) {
            #pragma unroll
            for (int h = 0; h < H; h++) {
                float p = __expf(e[h] - mh[h]);
                lh[h] = p;
                p_sh[wid][lane * H + h] = p;
            }
        }
        #pragma unroll
        for (int off = 1; off < 64; off <<= 1)
            #pragma unroll
            for (int h = 0; h < H; h++)
                lh[h] += __shfl_xor(lh[h], off);

        // ---- 4-deep unrolled gather: 4 loads in flight ----
        float acc1[FV], acc2[FV], acc3[FV];
        #pragma unroll
        for (int v = 0; v < FV; v++) { acc1[v] = 0.f; acc2[v] = 0.f; acc3[v] = 0.f; }
        int j = 0;
        for (; j + 4 <= deg; j += 4) {
            int s0 = __shfl(s, j + 0), s1 = __shfl(s, j + 1);
            int s2 = __shfl(s, j + 2), s3 = __shfl(s, j + 3);
            float p0 = p_sh[wid][(j + 0) * H + h_lane];
            float p1 = p_sh[wid][(j + 1) * H + h_lane];
            float p2 = p_sh[wid][(j + 2) * H + h_lane];
            float p3 = p_sh[wid][(j + 3) * H + h_lane];
            if constexpr (FV == 4) {
                gacc4(acc,  hfeat + (size_t)s0 * (H * C) + lane * 4, p0);
                gacc4(acc1, hfeat + (size_t)s1 * (H * C) + lane * 4, p1);
                gacc4(acc2, hfeat + (size_t)s2 * (H * C) + lane * 4, p2);
                gacc4(acc3, hfeat + (size_t)s3 * (H * C) + lane * 4, p3);
            } else {
                acc[0]  += p0 * __half2float(hfeat[(size_t)s0 * (H * C) + lane]);
                acc1[0] += p1 * __half2float(hfeat[(size_t)s1 * (H * C) + lane]);
                acc2[0] += p2 * __half2float(hfeat[(size_t)s2 * (H * C) + lane]);
                acc3[0] += p3 * __half2float(hfeat[(size_t)s3 * (H * C) + lane]);
            }
        }
        for (; j < deg; j++) {
            int s_j = __shfl(s, j);
            float pj = p_sh[wid][j * H + h_lane];
            if constexpr (FV == 4)
                gacc4(acc, hfeat + (size_t)s_j * (H * C) + lane * 4, pj);
            else
                acc[0] += pj * __half2float(hfeat[(size_t)s_j * (H * C) + lane]);
        }
        #pragma unroll
        for (int v = 0; v < FV; v++)
            acc[v] = (acc[v] + acc1[v]) + (acc2[v] + acc3[v]);
    } else {
        // ---------------- general path (deg > 64, rare) -------------------
        float mh[H];
        #pragma unroll
        for (int h = 0; h < H; h++) mh[h] = -3.0e38f;
        for (int i = lo + lane; i < hi; i += 64) {
            int s = colidx[i];
            #pragma unroll
            for (int h = 0; h < H; h++) {
                float v = a_s[s * H + h] + adp[h];
                v = (v > 0.f) ? v : 0.2f * v;
                mh[h] = fmaxf(mh[h], v);
            }
        }
        #pragma unroll
        for (int off = 1; off < 64; off <<= 1)
            #pragma unroll
            for (int h = 0; h < H; h++)
                mh[h] = fmaxf(mh[h], __shfl_xor(mh[h], off));

        for (int base = lo; base < hi; base += 64) {
            int i = base + lane;
            int s = 0;
            if (i < hi) {
                s = colidx[i];
                #pragma unroll
                for (int h = 0; h < H; h++) {
                    float v = a_s[s * H + h] + adp[h];
                    v = (v > 0.f) ? v : 0.2f * v;
                    float p = __expf(v - mh[h]);
                    lh[h] += p;
                    p_sh[wid][(i - base) * H + h] = p;
                }
            }
            int cnt = min(64, hi - base);
            for (int j = 0; j < cnt; j++) {
                int s_j = __shfl(s, j);
                float pj = p_sh[wid][j * H + h_lane];
                if constexpr (FV == 4)
                    gacc4(acc, hfeat + (size_t)s_j * (H * C) + lane * 4, pj);
                else
                    acc[0] += pj * __half2float(hfeat[(size_t)s_j * (H * C) + lane]);
            }
        }
        #pragma unroll
        for (int off = 1; off < 64; off <<= 1)
            #pragma unroll
            for (int h = 0; h < H; h++)
                lh[h] += __shfl_xor(lh[h], off);
    }

    // ---------------- epilogue ----------------
    float lsel = lh[0];
    #pragma unroll
    for (int h = 1; h < H; h++) if (h_lane == h) lsel = lh[h];
    const float inv = 1.0f / (lsel + 1e-16f);

    if constexpr (FV == 4) {           // H=4, C=64
        float vx = acc[0] * inv, vy = acc[1] * inv,
              vz = acc[2] * inv, vw = acc[3] * inv;
        vx += __shfl_xor(vx, 16); vy += __shfl_xor(vy, 16);
        vz += __shfl_xor(vz, 16); vw += __shfl_xor(vw, 16);
        vx += __shfl_xor(vx, 32); vy += __shfl_xor(vy, 32);
        vz += __shfl_xor(vz, 32); vw += __shfl_xor(vw, 32);
        if (lane < 16) {
            float4 bv = *reinterpret_cast<const float4*>(&bias[lane * 4]);
            float4 o;
            o.x = fmaxf(0.25f * vx + bv.x, 0.f);
            o.y = fmaxf(0.25f * vy + bv.y, 0.f);
            o.z = fmaxf(0.25f * vz + bv.z, 0.f);
            o.w = fmaxf(0.25f * vw + bv.w, 0.f);
            *reinterpret_cast<float4*>(&out[(size_t)d * C + lane * 4]) = o;
        }
    } else {                           // H=2, C=32
        float v = acc[0] * inv;
        v += __shfl_xor(v, 32);
        if (lane < 32)
            out[(size_t)d * C + lane] = fmaxf(0.5f * v + bias[lane], 0.f);
    }
}

// ---------------------------------------------------------------------------
// Global mean pool, one block per graph (batch sorted -> contiguous segments).
// ---------------------------------------------------------------------------
__global__ __launch_bounds__(256) void pool_pergraph(
        const float* __restrict__ h2, const int* __restrict__ batch,
        float* __restrict__ emb, int N)
{
    const int g = blockIdx.x;
    const int c = threadIdx.x & 31;
    const int r = threadIdx.x >> 5;

    __shared__ int bounds[2];
    if (threadIdx.x < 2) {
        int target = g + (int)threadIdx.x;
        int lo = 0, hi = N;
        while (lo < hi) {
            int mid = (lo + hi) >> 1;
            if (batch[mid] < target) lo = mid + 1; else hi = mid;
        }
        bounds[threadIdx.x] = lo;
    }
    __syncthreads();
    const int lo = bounds[0], hi = bounds[1];

    float acc = 0.f;
    for (int n = lo + r; n < hi; n += 8)
        acc += h2[(size_t)n * 32 + c];

    __shared__ float red[8][32];
    red[r][c] = acc;
    __syncthreads();
    if (r == 0) {
        float s = 0.f;
        #pragma unroll
        for (int i = 0; i < 8; i++) s += red[i][c];
        emb[g * 32 + c] = s / fmaxf((float)(hi - lo), 1.0f);
    }
}

// ---------------------------------------------------------------------------
// Heads: two 32->16->1 MLPs + sigmoid. out[0:64]=halt, out[64:128]=cont.
// ---------------------------------------------------------------------------
__global__ __launch_bounds__(64) void heads_kernel(
        const float* __restrict__ embg,
        const float* __restrict__ cW1, const float* __restrict__ cb1,
        const float* __restrict__ cW2, const float* __restrict__ cb2,
        const float* __restrict__ hW1, const float* __restrict__ hb1,
        const float* __restrict__ hW2, const float* __restrict__ hb2,
        float* __restrict__ out)
{
    int g = threadIdx.x;
    if (g >= G_GRAPHS) return;
    float emb[32];
    #pragma unroll
    for (int c = 0; c < 32; c++) emb[c] = embg[g * 32 + c];

    float sc = cb2[0];
    #pragma unroll
    for (int j = 0; j < 16; j++) {
        float s = cb1[j];
        #pragma unroll
        for (int c = 0; c < 32; c++) s += emb[c] * cW1[c * 16 + j];
        sc += fmaxf(s, 0.f) * cW2[j];
    }
    float cont = 1.0f / (1.0f + __expf(-sc));

    float sh = hb2[0];
    #pragma unroll
    for (int j = 0; j < 16; j++) {
        float s = hb1[j];
        #pragma unroll
        for (int c = 0; c < 32; c++) s += emb[c] * hW1[c * 16 + j];
        sh += fmaxf(s, 0.f) * hW2[j];
    }
    float halt = 1.0f / (1.0f + __expf(-sh));

    out[g] = halt;
    out[G_GRAPHS + g] = cont;
}

// ---------------------------------------------------------------------------
extern "C" void kernel_launch(void* const* d_in, const int* in_sizes, int n_in,
                              void* d_out, int out_size, void* d_ws, size_t ws_size,
                              hipStream_t stream)
{
    const float* x   = (const float*)d_in[0];
    const int*   ei  = (const int*)  d_in[1];
    const int*   bat = (const int*)  d_in[2];
    const float* W1  = (const float*)d_in[3];
    const float* as1 = (const float*)d_in[4];
    const float* ad1 = (const float*)d_in[5];
    const float* b1  = (const float*)d_in[6];
    const float* W2  = (const float*)d_in[7];
    const float* as2 = (const float*)d_in[8];
    const float* ad2 = (const float*)d_in[9];
    const float* b2  = (const float*)d_in[10];
    const float* cW1 = (const float*)d_in[11];
    const float* cb1 = (const float*)d_in[12];
    const float* cW2 = (const float*)d_in[13];
    const float* cb2 = (const float*)d_in[14];
    const float* hW1 = (const float*)d_in[15];
    const float* hb1 = (const float*)d_in[16];
    const float* hW2 = (const float*)d_in[17];
    const float* hb2 = (const float*)d_in[18];

    const int N    = in_sizes[2];           // 20000
    const int E0   = in_sizes[1] / 2;       // 320000
    const int Etot = E0 + N;                // + self loops
    const int IN   = in_sizes[0] / N;       // 128

    // ---- workspace carve (float-granular; half buffers use 2 halves/float)
    float* w = (float*)d_ws;
    size_t o = 0;
    __half* h1pre_h = (__half*)(w + o); o += (size_t)N * 128;  // [N,256] fp16
    __half* h2pre_h = (__half*)(w + o); o += (size_t)N * 32;   // [N,64]  fp16
    float* a_s1  = w + o; o += (size_t)N * 4;
    float* a_d1  = w + o; o += (size_t)N * 4;
    float* h1    = w + o; o += (size_t)N * 64;
    float* a_s2  = w + o; o += (size_t)N * 2;
    float* a_d2  = w + o; o += (size_t)N * 2;
    float* h2    = w + o; o += (size_t)N * 32;
    float* emb   = w + o; o += (size_t)G_GRAPHS * 32;
    int* rowptr  = (int*)(w + o); o += (size_t)N + 1;
    int* cursor  = (int*)(w + o); o += (size_t)N;
    int* deg     = (int*)(w + o); o += (size_t)N;
    int* colidx  = (int*)(w + o); o += (size_t)Etot;
    (void)ws_size; (void)n_in; (void)out_size;

    const dim3 blk(256);
    const int eb = (Etot + 255) / 256;
    const int nb4 = (N + 3) / 4;

    // ---- CSR build (once; shared by both layers) ----
    hipMemsetAsync(deg, 0, (size_t)N * sizeof(int), stream);
    csr_count<<<eb, blk, 0, stream>>>(ei, deg, E0, Etot);
    csr_scan<<<1, 1024, 0, stream>>>(deg, rowptr, cursor, N);
    csr_fill<<<eb, blk, 0, stream>>>(ei, cursor, colidx, E0, Etot);

    // ---- layer 1: GAT(128 -> 4 heads x 64, head-mean) + relu ----
    gemm_fp32<<<dim3((N + 63) / 64, 4), blk, 0, stream>>>(x, W1, h1pre_h, N, 256, IN);
    att_coef<4, 64><<<(N * 4 + 255) / 256, blk, 0, stream>>>(h1pre_h, as1, ad1, a_s1, a_d1, N);
    gat_dst<4, 64><<<nb4, blk, 0, stream>>>(rowptr, colidx, h1pre_h, a_s1, a_d1, b1, h1, N);

    // ---- layer 2: GAT(64 -> 2 heads x 32, head-mean) + relu ----
    gemm_fp32<<<dim3((N + 63) / 64, 1), blk, 0, stream>>>(h1, W2, h2pre_h, N, 64, 64);
    att_coef<2, 32><<<(N * 2 + 255) / 256, blk, 0, stream>>>(h2pre_h, as2, ad2, a_s2, a_d2, N);
    gat_dst<2, 32><<<nb4, blk, 0, stream>>>(rowptr, colidx, h2pre_h, a_s2, a_d2, b2, h2, N);

    // ---- pool + heads (no atomics: batch is sorted) ----
    pool_pergraph<<<G_GRAPHS, blk, 0, stream>>>(h2, bat, emb, N);
    heads_kernel<<<1, 64, 0, stream>>>(emb, cW1, cb1, cW2, cb2,
                                       hW1, hb1, hW2, hb2, (float*)d_out);
}

// Round 6
// 257.323 us; speedup vs baseline: 2.4554x; 1.0596x over previous
//
#include <hip/hip_runtime.h>
#include <hip/hip_fp16.h>

// ---------------------------------------------------------------------------
// GAT policy module: 2x GAT layer (head-mean) + mean-pool + 2 MLP heads.
// Round 5: MFMA fp16 GEMM (16x16x32_f16, fp32 accum) with the attention
// coefficient reduction (a_src/a_dst) fused into the GEMM epilogue;
// gat_dst layer-1 writes h1 in fp16 directly for GEMM2.
// Fragment layouts (HW-verified, learn_hip m89/m91/m120):
//   A[m=lane&15][k=quad*8+j], B[k=quad*8+j][n=lane&15],
//   C/D: col=lane&15, row=quad*4+reg.
// ---------------------------------------------------------------------------

#define G_GRAPHS 64

using half8   = __attribute__((ext_vector_type(8))) _Float16;
using half4v  = __attribute__((ext_vector_type(4))) _Float16;
using floatx4 = __attribute__((ext_vector_type(4))) float;

// ---------------------------------------------------------------------------
// fp32 -> fp16 cast, 4 elems/thread. n4 = count/4 (all counts %4==0).
// ---------------------------------------------------------------------------
__global__ __launch_bounds__(256) void cast_f16(
        const float* __restrict__ src, _Float16* __restrict__ dst, int n4)
{
    int i = blockIdx.x * 256 + threadIdx.x;
    if (i >= n4) return;
    float4 v = reinterpret_cast<const float4*>(src)[i];
    half4v h = { (_Float16)v.x, (_Float16)v.y, (_Float16)v.z, (_Float16)v.w };
    reinterpret_cast<half4v*>(dst)[i] = h;
}

// ---------------------------------------------------------------------------
// MFMA fp16 GEMM (64x64 tile per block, whole K in LDS) + fused att-coef.
//   Ch[m, col0+*] = A[m,:K] @ B[:K, col0+*]   (fp16 out, fp32 accum)
//   a_s[m, head] = sum_c Ch[m, head-cols c] * att_s[head, c]  (fp32, from acc)
// HPB = heads per 64-col block (L1: 1 head x 64ch, L2: 2 heads x 32ch).
// ---------------------------------------------------------------------------
template<int K, int HPB>
__global__ __launch_bounds__(256) void gemm_mfma_att(
        const _Float16* __restrict__ A, const _Float16* __restrict__ B,
        _Float16* __restrict__ Ch, const float* __restrict__ att_s,
        const float* __restrict__ att_d, float* __restrict__ a_s,
        float* __restrict__ a_d, int M, int Ntot, int Htot)
{
    constexpr int CPH = 64 / HPB;        // channels per head
    constexpr int NTH = 4 / HPB;         // col-tiles (of 16) per head
    __shared__ _Float16 As[64][K + 8];   // row-major, +8 pad (2-way only)
    __shared__ _Float16 Bt[64][K + 8];   // transposed: Bt[n][k]

    const int tid  = threadIdx.x;
    const int row0 = blockIdx.x * 64;
    const int col0 = blockIdx.y * 64;

    // ---- stage A tile: 64 rows x K halves ----
    {
        int row = tid >> 2;
        int kc  = (tid & 3) * (K / 4);
        int gr  = row0 + row;
        #pragma unroll
        for (int i = 0; i < K / 32; i++) {
            half8 v = {};
            if (gr < M)
                v = *reinterpret_cast<const half8*>(&A[(size_t)gr * K + kc + i * 8]);
            *reinterpret_cast<half8*>(&As[row][kc + i * 8]) = v;
        }
    }
    // ---- stage B tile transposed: Bt[n][k] ----
    {
        #pragma unroll
        for (int i = 0; i < K / 16; i++) {
            int id = tid + 256 * i;
            int k  = id >> 4;
            int n4 = (id & 15) * 4;
            half4v v = *reinterpret_cast<const half4v*>(&B[(size_t)k * Ntot + col0 + n4]);
            Bt[n4 + 0][k] = v[0]; Bt[n4 + 1][k] = v[1];
            Bt[n4 + 2][k] = v[2]; Bt[n4 + 3][k] = v[3];
        }
    }
    __syncthreads();

    const int wid  = tid >> 6;
    const int lane = tid & 63;
    const int r    = lane & 15;
    const int quad = lane >> 4;
    const int rw0  = wid * 16;           // wave's 16-row slice

    floatx4 acc[4] = {};
    #pragma unroll
    for (int s = 0; s < K / 32; s++) {
        half8 af = *reinterpret_cast<const half8*>(&As[rw0 + r][s * 32 + quad * 8]);
        #pragma unroll
        for (int nt = 0; nt < 4; nt++) {
            half8 bf = *reinterpret_cast<const half8*>(&Bt[nt * 16 + r][s * 32 + quad * 8]);
            acc[nt] = __builtin_amdgcn_mfma_f32_16x16x32_f16(af, bf, acc[nt], 0, 0, 0);
        }
    }

    // ---- store Ch (fp16) ----
    #pragma unroll
    for (int nt = 0; nt < 4; nt++) {
        #pragma unroll
        for (int reg = 0; reg < 4; reg++) {
            int gr = row0 + rw0 + quad * 4 + reg;
            if (gr < M)
                Ch[(size_t)gr * Ntot + col0 + nt * 16 + r] = (_Float16)acc[nt][reg];
        }
    }

    // ---- fused att-coef: per-row dot with att weights, 16-lane reduce ----
    float ps[HPB][4], pd[HPB][4];
    #pragma unroll
    for (int hl = 0; hl < HPB; hl++)
        #pragma unroll
        for (int reg = 0; reg < 4; reg++) { ps[hl][reg] = 0.f; pd[hl][reg] = 0.f; }

    #pragma unroll
    for (int nt = 0; nt < 4; nt++) {
        int hl = nt / NTH;
        int cl = (nt % NTH) * 16 + r;
        int hglob = blockIdx.y * HPB + hl;
        float ws = att_s[hglob * CPH + cl];
        float wd = att_d[hglob * CPH + cl];
        #pragma unroll
        for (int reg = 0; reg < 4; reg++) {
            ps[hl][reg] += acc[nt][reg] * ws;
            pd[hl][reg] += acc[nt][reg] * wd;
        }
    }
    #pragma unroll
    for (int off = 1; off < 16; off <<= 1)
        #pragma unroll
        for (int hl = 0; hl < HPB; hl++)
            #pragma unroll
            for (int reg = 0; reg < 4; reg++) {
                ps[hl][reg] += __shfl_xor(ps[hl][reg], off);
                pd[hl][reg] += __shfl_xor(pd[hl][reg], off);
            }
    if (r == 0) {
        #pragma unroll
        for (int reg = 0; reg < 4; reg++) {
            int gr = row0 + rw0 + quad * 4 + reg;
            if (gr < M) {
                #pragma unroll
                for (int hl = 0; hl < HPB; hl++) {
                    int hglob = blockIdx.y * HPB + hl;
                    a_s[gr * Htot + hglob] = ps[hl][reg];
                    a_d[gr * Htot + hglob] = pd[hl][reg];
                }
            }
        }
    }
}

// ---------------------------------------------------------------------------
// CSR build: degree count -> exclusive scan -> bucket fill.
// ---------------------------------------------------------------------------
__global__ __launch_bounds__(256) void csr_count(
        const int* __restrict__ ei, int* __restrict__ deg, int E0, int Etot)
{
    int idx = blockIdx.x * 256 + threadIdx.x;
    if (idx >= Etot) return;
    int dst = (idx < E0) ? ei[E0 + idx] : (idx - E0);
    atomicAdd(&deg[dst], 1);
}

__global__ __launch_bounds__(1024) void csr_scan(
        const int* __restrict__ deg, int* __restrict__ rowptr,
        int* __restrict__ cursor, int N)
{
    const int tid = threadIdx.x;
    const int items = (N + 1023) >> 10;
    const int b = tid * items;
    int sum = 0;
    for (int k = 0; k < items; k++) {
        int i = b + k;
        sum += (i < N) ? deg[i] : 0;
    }
    __shared__ int smem[1024];
    smem[tid] = sum;
    __syncthreads();
    for (int off = 1; off < 1024; off <<= 1) {
        int t = (tid >= off) ? smem[tid - off] : 0;
        __syncthreads();
        smem[tid] += t;
        __syncthreads();
    }
    int excl = smem[tid] - sum;
    for (int k = 0; k < items; k++) {
        int i = b + k;
        if (i < N) {
            rowptr[i] = excl; cursor[i] = excl;
            excl += deg[i];
        }
    }
    if (tid == 1023) rowptr[N] = excl;
}

__global__ __launch_bounds__(256) void csr_fill(
        const int* __restrict__ ei, int* __restrict__ cursor,
        int* __restrict__ col, int E0, int Etot)
{
    int idx = blockIdx.x * 256 + threadIdx.x;
    if (idx >= Etot) return;
    int src = (idx < E0) ? ei[idx]      : (idx - E0);
    int dst = (idx < E0) ? ei[E0 + idx] : (idx - E0);
    int pos = atomicAdd(&cursor[dst], 1);
    col[pos] = src;
}

// ---------------------------------------------------------------------------
// fp16 gather helper: 8B load = 4 halves; FMA into 4-float acc.
// ---------------------------------------------------------------------------
__device__ inline void gacc4(float* a, const __half* hp, float p) {
    float2 raw = *reinterpret_cast<const float2*>(hp);
    __half2 h0 = *reinterpret_cast<__half2*>(&raw.x);
    __half2 h1 = *reinterpret_cast<__half2*>(&raw.y);
    float2 f0 = __half22float2(h0), f1 = __half22float2(h1);
    a[0] += p * f0.x; a[1] += p * f0.y; a[2] += p * f1.x; a[3] += p * f1.y;
}

// ---------------------------------------------------------------------------
// Fused GAT aggregation, one wave per dst node. OUT_HALF: write fp16 (layer 1
// output feeds the fp16 MFMA GEMM of layer 2).
// ---------------------------------------------------------------------------
template<int H, int C, bool OUT_HALF>
__global__ __launch_bounds__(256) void gat_dst(
        const int* __restrict__ rowptr, const int* __restrict__ colidx,
        const __half* __restrict__ hfeat, const float* __restrict__ a_s,
        const float* __restrict__ a_d, const float* __restrict__ bias,
        void* __restrict__ out_v, int N)
{
    constexpr int FV = (H * C) / 64;
    const int wid  = threadIdx.x >> 6;
    const int lane = threadIdx.x & 63;
    const int d = blockIdx.x * 4 + wid;

    __shared__ float p_sh[4][64 * H];

    if (d >= N) return;
    const int lo = rowptr[d], hi = rowptr[d + 1];
    const int deg = hi - lo;
    const int h_lane = (lane * FV) / C;

    float adp[H];
    #pragma unroll
    for (int h = 0; h < H; h++) adp[h] = a_d[d * H + h];

    float lh[H];
    #pragma unroll
    for (int h = 0; h < H; h++) lh[h] = 0.f;
    float acc[FV];
    #pragma unroll
    for (int v = 0; v < FV; v++) acc[v] = 0.f;

    if (deg <= 64) {
        int s = 0;
        float e[H];
        const bool valid = lane < deg;
        if (valid) {
            s = colidx[lo + lane];
            if constexpr (H == 4) {
                float4 av = *reinterpret_cast<const float4*>(&a_s[s * 4]);
                float ev[4] = {av.x + adp[0], av.y + adp[1],
                               av.z + adp[2], av.w + adp[3]};
                #pragma unroll
                for (int h = 0; h < 4; h++)
                    e[h] = (ev[h] > 0.f) ? ev[h] : 0.2f * ev[h];
            } else {
                float2 av = *reinterpret_cast<const float2*>(&a_s[s * 2]);
                float ev[2] = {av.x + adp[0], av.y + adp[1]};
                #pragma unroll
                for (int h = 0; h < 2; h++)
                    e[h] = (ev[h] > 0.f) ? ev[h] : 0.2f * ev[h];
            }
        } else {
            #pragma unroll
            for (int h = 0; h < H; h++) e[h] = -3.0e38f;
        }
        float mh[H];
        #pragma unroll
        for (int h = 0; h < H; h++) mh[h] = e[h];
        #pragma unroll
        for (int off = 1; off < 64; off <<= 1)
            #pragma unroll
            for (int h = 0; h < H; h++)
                mh[h] = fmaxf(mh[h], __shfl_xor(mh[h], off));

        if (valid) {
            #pragma unroll
            for (int h = 0; h < H; h++) {
                float p = __expf(e[h] - mh[h]);
                lh[h] = p;
                p_sh[wid][lane * H + h] = p;
            }
        }
        #pragma unroll
        for (int off = 1; off < 64; off <<= 1)
            #pragma unroll
            for (int h = 0; h < H; h++)
                lh[h] += __shfl_xor(lh[h], off);

        float acc1[FV], acc2[FV], acc3[FV];
        #pragma unroll
        for (int v = 0; v < FV; v++) { acc1[v] = 0.f; acc2[v] = 0.f; acc3[v] = 0.f; }
        int j = 0;
        for (; j + 4 <= deg; j += 4) {
            int s0 = __shfl(s, j + 0), s1 = __shfl(s, j + 1);
            int s2 = __shfl(s, j + 2), s3 = __shfl(s, j + 3);
            float p0 = p_sh[wid][(j + 0) * H + h_lane];
            float p1 = p_sh[wid][(j + 1) * H + h_lane];
            float p2 = p_sh[wid][(j + 2) * H + h_lane];
            float p3 = p_sh[wid][(j + 3) * H + h_lane];
            if constexpr (FV == 4) {
                gacc4(acc,  hfeat + (size_t)s0 * (H * C) + lane * 4, p0);
                gacc4(acc1, hfeat + (size_t)s1 * (H * C) + lane * 4, p1);
                gacc4(acc2, hfeat + (size_t)s2 * (H * C) + lane * 4, p2);
                gacc4(acc3, hfeat + (size_t)s3 * (H * C) + lane * 4, p3);
            } else {
                acc[0]  += p0 * __half2float(hfeat[(size_t)s0 * (H * C) + lane]);
                acc1[0] += p1 * __half2float(hfeat[(size_t)s1 * (H * C) + lane]);
                acc2[0] += p2 * __half2float(hfeat[(size_t)s2 * (H * C) + lane]);
                acc3[0] += p3 * __half2float(hfeat[(size_t)s3 * (H * C) + lane]);
            }
        }
        for (; j < deg; j++) {
            int s_j = __shfl(s, j);
            float pj = p_sh[wid][j * H + h_lane];
            if constexpr (FV == 4)
                gacc4(acc, hfeat + (size_t)s_j * (H * C) + lane * 4, pj);
            else
                acc[0] += pj * __half2float(hfeat[(size_t)s_j * (H * C) + lane]);
        }
        #pragma unroll
        for (int v = 0; v < FV; v++)
            acc[v] = (acc[v] + acc1[v]) + (acc2[v] + acc3[v]);
    } else {
        float mh[H];
        #pragma unroll
        for (int h = 0; h < H; h++) mh[h] = -3.0e38f;
        for (int i = lo + lane; i < hi; i += 64) {
            int s = colidx[i];
            #pragma unroll
            for (int h = 0; h < H; h++) {
                float v = a_s[s * H + h] + adp[h];
                v = (v > 0.f) ? v : 0.2f * v;
                mh[h] = fmaxf(mh[h], v);
            }
        }
        #pragma unroll
        for (int off = 1; off < 64; off <<= 1)
            #pragma unroll
            for (int h = 0; h < H; h++)
                mh[h] = fmaxf(mh[h], __shfl_xor(mh[h], off));

        for (int base = lo; base < hi; base += 64) {
            int i = base + lane;
            int s = 0;
            if (i < hi) {
                s = colidx[i];
                #pragma unroll
                for (int h = 0; h < H; h++) {
                    float v = a_s[s * H + h] + adp[h];
                    v = (v > 0.f) ? v : 0.2f * v;
                    float p = __expf(v - mh[h]);
                    lh[h] += p;
                    p_sh[wid][(i - base) * H + h] = p;
                }
            }
            int cnt = min(64, hi - base);
            for (int j = 0; j < cnt; j++) {
                int s_j = __shfl(s, j);
                float pj = p_sh[wid][j * H + h_lane];
                if constexpr (FV == 4)
                    gacc4(acc, hfeat + (size_t)s_j * (H * C) + lane * 4, pj);
                else
                    acc[0] += pj * __half2float(hfeat[(size_t)s_j * (H * C) + lane]);
            }
        }
        #pragma unroll
        for (int off = 1; off < 64; off <<= 1)
            #pragma unroll
            for (int h = 0; h < H; h++)
                lh[h] += __shfl_xor(lh[h], off);
    }

    // ---------------- epilogue ----------------
    float lsel = lh[0];
    #pragma unroll
    for (int h = 1; h < H; h++) if (h_lane == h) lsel = lh[h];
    const float inv = 1.0f / (lsel + 1e-16f);

    if constexpr (FV == 4) {           // H=4, C=64
        float vx = acc[0] * inv, vy = acc[1] * inv,
              vz = acc[2] * inv, vw = acc[3] * inv;
        vx += __shfl_xor(vx, 16); vy += __shfl_xor(vy, 16);
        vz += __shfl_xor(vz, 16); vw += __shfl_xor(vw, 16);
        vx += __shfl_xor(vx, 32); vy += __shfl_xor(vy, 32);
        vz += __shfl_xor(vz, 32); vw += __shfl_xor(vw, 32);
        if (lane < 16) {
            float4 bv = *reinterpret_cast<const float4*>(&bias[lane * 4]);
            float ox = fmaxf(0.25f * vx + bv.x, 0.f);
            float oy = fmaxf(0.25f * vy + bv.y, 0.f);
            float oz = fmaxf(0.25f * vz + bv.z, 0.f);
            float ow = fmaxf(0.25f * vw + bv.w, 0.f);
            if constexpr (OUT_HALF) {
                half4v hv = { (_Float16)ox, (_Float16)oy, (_Float16)oz, (_Float16)ow };
                *reinterpret_cast<half4v*>((_Float16*)out_v + (size_t)d * C + lane * 4) = hv;
            } else {
                float4 o = make_float4(ox, oy, oz, ow);
                *reinterpret_cast<float4*>((float*)out_v + (size_t)d * C + lane * 4) = o;
            }
        }
    } else {                           // H=2, C=32
        float v = acc[0] * inv;
        v += __shfl_xor(v, 32);
        if (lane < 32) {
            float o = fmaxf(0.5f * v + bias[lane], 0.f);
            if constexpr (OUT_HALF)
                ((_Float16*)out_v)[(size_t)d * C + lane] = (_Float16)o;
            else
                ((float*)out_v)[(size_t)d * C + lane] = o;
        }
    }
}

// ---------------------------------------------------------------------------
// Global mean pool, one block per graph (batch sorted -> contiguous segments).
// ---------------------------------------------------------------------------
__global__ __launch_bounds__(256) void pool_pergraph(
        const float* __restrict__ h2, const int* __restrict__ batch,
        float* __restrict__ emb, int N)
{
    const int g = blockIdx.x;
    const int c = threadIdx.x & 31;
    const int r = threadIdx.x >> 5;

    __shared__ int bounds[2];
    if (threadIdx.x < 2) {
        int target = g + (int)threadIdx.x;
        int lo = 0, hi = N;
        while (lo < hi) {
            int mid = (lo + hi) >> 1;
            if (batch[mid] < target) lo = mid + 1; else hi = mid;
        }
        bounds[threadIdx.x] = lo;
    }
    __syncthreads();
    const int lo = bounds[0], hi = bounds[1];

    float acc = 0.f;
    for (int n = lo + r; n < hi; n += 8)
        acc += h2[(size_t)n * 32 + c];

    __shared__ float red[8][32];
    red[r][c] = acc;
    __syncthreads();
    if (r == 0) {
        float s = 0.f;
        #pragma unroll
        for (int i = 0; i < 8; i++) s += red[i][c];
        emb[g * 32 + c] = s / fmaxf((float)(hi - lo), 1.0f);
    }
}

// ---------------------------------------------------------------------------
// Heads: two 32->16->1 MLPs + sigmoid. out[0:64]=halt, out[64:128]=cont.
// ---------------------------------------------------------------------------
__global__ __launch_bounds__(64) void heads_kernel(
        const float* __restrict__ embg,
        const float* __restrict__ cW1, const float* __restrict__ cb1,
        const float* __restrict__ cW2, const float* __restrict__ cb2,
        const float* __restrict__ hW1, const float* __restrict__ hb1,
        const float* __restrict__ hW2, const float* __restrict__ hb2,
        float* __restrict__ out)
{
    int g = threadIdx.x;
    if (g >= G_GRAPHS) return;
    float emb[32];
    #pragma unroll
    for (int c = 0; c < 32; c++) emb[c] = embg[g * 32 + c];

    float sc = cb2[0];
    #pragma unroll
    for (int j = 0; j < 16; j++) {
        float s = cb1[j];
        #pragma unroll
        for (int c = 0; c < 32; c++) s += emb[c] * cW1[c * 16 + j];
        sc += fmaxf(s, 0.f) * cW2[j];
    }
    float cont = 1.0f / (1.0f + __expf(-sc));

    float sh = hb2[0];
    #pragma unroll
    for (int j = 0; j < 16; j++) {
        float s = hb1[j];
        #pragma unroll
        for (int c = 0; c < 32; c++) s += emb[c] * hW1[c * 16 + j];
        sh += fmaxf(s, 0.f) * hW2[j];
    }
    float halt = 1.0f / (1.0f + __expf(-sh));

    out[g] = halt;
    out[G_GRAPHS + g] = cont;
}

// ---------------------------------------------------------------------------
extern "C" void kernel_launch(void* const* d_in, const int* in_sizes, int n_in,
                              void* d_out, int out_size, void* d_ws, size_t ws_size,
                              hipStream_t stream)
{
    const float* x   = (const float*)d_in[0];
    const int*   ei  = (const int*)  d_in[1];
    const int*   bat = (const int*)  d_in[2];
    const float* W1  = (const float*)d_in[3];
    const float* as1 = (const float*)d_in[4];
    const float* ad1 = (const float*)d_in[5];
    const float* b1  = (const float*)d_in[6];
    const float* W2  = (const float*)d_in[7];
    const float* as2 = (const float*)d_in[8];
    const float* ad2 = (const float*)d_in[9];
    const float* b2  = (const float*)d_in[10];
    const float* cW1 = (const float*)d_in[11];
    const float* cb1 = (const float*)d_in[12];
    const float* cW2 = (const float*)d_in[13];
    const float* cb2 = (const float*)d_in[14];
    const float* hW1 = (const float*)d_in[15];
    const float* hb1 = (const float*)d_in[16];
    const float* hW2 = (const float*)d_in[17];
    const float* hb2 = (const float*)d_in[18];

    const int N    = in_sizes[2];           // 20000
    const int E0   = in_sizes[1] / 2;       // 320000
    const int Etot = E0 + N;                // + self loops
    const int IN   = in_sizes[0] / N;       // 128

    // ---- workspace carve (float-granular) ----
    float* w = (float*)d_ws;
    size_t o = 0;
    _Float16* x_h     = (_Float16*)(w + o); o += (size_t)N * IN / 2;   // [N,128]
    _Float16* W1_h    = (_Float16*)(w + o); o += (size_t)IN * 256 / 2; // [128,256]
    _Float16* W2_h    = (_Float16*)(w + o); o += (size_t)64 * 64 / 2;  // [64,64]
    _Float16* h1pre_h = (_Float16*)(w + o); o += (size_t)N * 128;      // [N,256]
    _Float16* h1_h    = (_Float16*)(w + o); o += (size_t)N * 32;       // [N,64]
    _Float16* h2pre_h = (_Float16*)(w + o); o += (size_t)N * 32;       // [N,64]
    float* a_s1  = w + o; o += (size_t)N * 4;
    float* a_d1  = w + o; o += (size_t)N * 4;
    float* a_s2  = w + o; o += (size_t)N * 2;
    float* a_d2  = w + o; o += (size_t)N * 2;
    float* h2    = w + o; o += (size_t)N * 32;
    float* emb   = w + o; o += (size_t)G_GRAPHS * 32;
    int* rowptr  = (int*)(w + o); o += (size_t)N + 1;
    int* cursor  = (int*)(w + o); o += (size_t)N;
    int* deg     = (int*)(w + o); o += (size_t)N;
    int* colidx  = (int*)(w + o); o += (size_t)Etot;
    (void)ws_size; (void)n_in; (void)out_size;

    const dim3 blk(256);
    const int eb  = (Etot + 255) / 256;
    const int nb4 = (N + 3) / 4;
    const int mb  = (N + 63) / 64;

    // ---- casts + CSR build ----
    hipMemsetAsync(deg, 0, (size_t)N * sizeof(int), stream);
    cast_f16<<<(N * IN / 4 + 255) / 256, blk, 0, stream>>>(x, x_h, N * IN / 4);
    cast_f16<<<(IN * 256 / 4 + 255) / 256, blk, 0, stream>>>(W1, W1_h, IN * 256 / 4);
    cast_f16<<<(64 * 64 / 4 + 255) / 256, blk, 0, stream>>>(W2, W2_h, 64 * 64 / 4);
    csr_count<<<eb, blk, 0, stream>>>(ei, deg, E0, Etot);
    csr_scan<<<1, 1024, 0, stream>>>(deg, rowptr, cursor, N);
    csr_fill<<<eb, blk, 0, stream>>>(ei, cursor, colidx, E0, Etot);

    // ---- layer 1: GAT(128 -> 4 heads x 64, head-mean) + relu ----
    gemm_mfma_att<128, 1><<<dim3(mb, 4), blk, 0, stream>>>(
        x_h, W1_h, h1pre_h, as1, ad1, a_s1, a_d1, N, 256, 4);
    gat_dst<4, 64, true><<<nb4, blk, 0, stream>>>(
        rowptr, colidx, (const __half*)h1pre_h, a_s1, a_d1, b1, h1_h, N);

    // ---- layer 2: GAT(64 -> 2 heads x 32, head-mean) + relu ----
    gemm_mfma_att<64, 2><<<dim3(mb, 1), blk, 0, stream>>>(
        h1_h, W2_h, h2pre_h, as2, ad2, a_s2, a_d2, N, 64, 2);
    gat_dst<2, 32, false><<<nb4, blk, 0, stream>>>(
        rowptr, colidx, (const __half*)h2pre_h, a_s2, a_d2, b2, h2, N);

    // ---- pool + heads (no atomics: batch is sorted) ----
    pool_pergraph<<<G_GRAPHS, blk, 0, stream>>>(h2, bat, emb, N);
    heads_kernel<<<1, 64, 0, stream>>>(emb, cW1, cb1, cW2, cb2,
                                       hW1, hb1, hW2, hb2, (float*)d_out);
}